// Round 6
// baseline (504.449 us; speedup 1.0000x reference)
//
#include <hip/hip_runtime.h>
#include <math.h>

#define B_ 4
#define CCH 128
#define HH 64
#define WW 64
#define LL 4096
#define NCHK 64

__device__ __forceinline__ float siluf(float x) { return x / (1.f + __expf(-x)); }
__device__ __forceinline__ float softplusf(float x) { return (x > 20.f) ? x : log1pf(__expf(x)); }
// swizzled [n][l] layout, pitch 64: phys = n*64 + (((l>>2) ^ ((n>>2)&15))<<2 | (l&3))
__device__ __forceinline__ int swz(int n, int l) {
  return (n << 6) + ((((l >> 2) ^ ((n >> 2) & 15)) << 2) | (l & 3));
}

// ---------------- seed tokenize v2 ----------------
__global__ __launch_bounds__(256) void k_seedtok(const float* __restrict__ x,
    const float* __restrict__ w, const float* __restrict__ bias, float* __restrict__ gf)
{
  __shared__ float tile[128*65];
  __shared__ float sw[8*128];
  __shared__ float bl[8];
  int tid = threadIdx.x;
  int b = blockIdx.x >> 6;
  int l0 = (blockIdx.x & 63) << 6;
  for (int i = tid; i < 1024; i += 256) sw[i] = w[i];
  if (tid < 8) bl[tid] = bias[tid];
  for (int i = tid; i < 8192; i += 256) {
    int l = i & 63, c = i >> 6;
    tile[c*65 + l] = x[((size_t)b*CCH + c)*LL + l0 + l];
  }
  __syncthreads();
  int l = tid & 63, q = tid >> 6;
  float a0 = bl[2*q], a1 = bl[2*q+1];
  const float* w0 = &sw[(2*q)*128];
  const float* w1 = &sw[(2*q+1)*128];
#pragma unroll 4
  for (int c = 0; c < 128; ++c) {
    float xv = tile[c*65 + l];
    a0 += xv * w0[c];
    a1 += xv * w1[c];
  }
  *(float2*)&gf[((size_t)b*LL + l0 + l)*8 + 2*q] = make_float2(a0, a1);
}

// ---------------- fused in-projection + conv3 + silu + softplus(dt) (seed path) ----------------
template<int DIN, int NZ, int NDS, int NDT>
__global__ __launch_bounds__(256) void k_inproj(
    const float* __restrict__ src, int srcMode,
    const float* __restrict__ in_w, const float* __restrict__ in_b,
    const float* __restrict__ conv_w, const float* __restrict__ conv_b,
    const float* __restrict__ dt_bias,
    float* __restrict__ zb, float* __restrict__ dtb,
    float* __restrict__ xsb, float* __restrict__ Bb, float* __restrict__ Cb)
{
  constexpr int NXBC = NZ + 2*NDS;
  constexpr int NTOT = 2*NZ + 2*NDS + NDT;
  constexpr int NZQ  = NZ/4;
  constexpr int NDSQ = NDS/4;
  constexpr int XP   = DIN + 1;
  __shared__ float xt[66*XP];
  __shared__ __align__(16) float wl[NTOT*DIN];
  __shared__ float cwl[NXBC*3];
  __shared__ float cbl[NXBC];
  __shared__ float ibl[NTOT];
  __shared__ float dts[64*NDT];
  __shared__ float hp[NXBC*2];
  int tid = threadIdx.x;
  int seq = blockIdx.x >> 6;
  int l0  = (blockIdx.x & 63) << 6;
  for (int i = tid; i < NTOT*DIN; i += 256) wl[i] = in_w[i];
  for (int i = tid; i < NXBC*3; i += 256) cwl[i] = conv_w[i];
  for (int i = tid; i < NXBC; i += 256) cbl[i] = conv_b[i];
  for (int i = tid; i < NTOT; i += 256) ibl[i] = in_b[i];
  const float* sp; int sstr;
  if (srcMode == 0) { sp = src + (size_t)seq*LL*DIN; sstr = DIN; }
  else { sp = src + (size_t)(seq & 3)*LL*CCH + (seq >> 2)*16; sstr = CCH; }
  for (int i = tid; i < 66*DIN; i += 256) {
    int r = i / DIN, d = i % DIN;
    int l = l0 - 2 + r;
    xt[r*XP + d] = (l >= 0) ? sp[(size_t)l*sstr + d] : 0.f;
  }
  __syncthreads();
  for (int i = tid; i < 2*NXBC; i += 256) {
    int t = i & 1, ch = i >> 1;
    const float* wr = &wl[(NZ + ch)*DIN];
    const float* xp = &xt[t*XP];
    float acc = 0.f;
#pragma unroll
    for (int d = 0; d < DIN; ++d) acc += xp[d]*wr[d];
    hp[ch*2 + t] = acc;
  }
  __syncthreads();
  int l = tid & 63, w4 = tid >> 6;
  float xr2[DIN];
#pragma unroll
  for (int d = 0; d < DIN; ++d) xr2[d] = xt[(l+2)*XP + d];
  auto dotw = [&](int row) -> float {
    const float* wr = &wl[row*DIN];
    float acc = 0.f;
#pragma unroll
    for (int q4 = 0; q4 < DIN/4; ++q4) {
      float4 wv = *(const float4*)(wr + 4*q4);
      acc += xr2[4*q4]*wv.x + xr2[4*q4+1]*wv.y + xr2[4*q4+2]*wv.z + xr2[4*q4+3]*wv.w;
    }
    return acc;
  };
  size_t gl = (size_t)seq*LL + l0 + l;
  int tok = l0 + l;
  float v0ok = (tok >= 2) ? 1.f : 0.f;
  float v1ok = (tok >= 1) ? 1.f : 0.f;
  {
    float zv[NZQ];
#pragma unroll
    for (int j = 0; j < NZQ; ++j) {
      int row = w4*NZQ + j;
      zv[j] = ibl[row] + dotw(row);
    }
#pragma unroll
    for (int g = 0; g < NZQ/4; ++g)
      *(float4*)&zb[gl*NZ + w4*NZQ + 4*g] = make_float4(zv[4*g], zv[4*g+1], zv[4*g+2], zv[4*g+3]);
  }
  if (w4 < NDT) {
    int row = NTOT - NDT + w4;
    dts[l*NDT + w4] = softplusf(ibl[row] + dt_bias[w4] + dotw(row));
  }
  auto convch = [&](int ch) -> float {
    int row = NZ + ch;
    float pm = dotw(row);
    float m1 = __shfl_up(pm, 1, 64);
    float m2 = __shfl_up(pm, 2, 64);
    float h0 = hp[ch*2 + 0], h1 = hp[ch*2 + 1];
    if (l == 0) m1 = h1;
    m2 = (l == 0) ? h0 : ((l == 1) ? h1 : m2);
    float ib = ibl[row];
    float conv = cbl[ch] + (m2+ib)*v0ok*cwl[ch*3+0] + (m1+ib)*v1ok*cwl[ch*3+1] + (pm+ib)*cwl[ch*3+2];
    return siluf(conv);
  };
  {
    float xv[NZQ];
#pragma unroll
    for (int j = 0; j < NZQ; ++j) xv[j] = convch(w4*NZQ + j);
#pragma unroll
    for (int g = 0; g < NZQ/4; ++g)
      *(float4*)&xsb[gl*NZ + w4*NZQ + 4*g] = make_float4(xv[4*g], xv[4*g+1], xv[4*g+2], xv[4*g+3]);
  }
  {
    float bv[NDSQ];
#pragma unroll
    for (int j = 0; j < NDSQ; ++j) bv[j] = convch(NZ + w4*NDSQ + j);
#pragma unroll
    for (int g = 0; g < NDSQ/4; ++g)
      *(float4*)&Bb[gl*NDS + w4*NDSQ + 4*g] = make_float4(bv[4*g], bv[4*g+1], bv[4*g+2], bv[4*g+3]);
  }
  {
    float cv[NDSQ];
#pragma unroll
    for (int j = 0; j < NDSQ; ++j) cv[j] = convch(NZ + NDS + w4*NDSQ + j);
#pragma unroll
    for (int g = 0; g < NDSQ/4; ++g)
      *(float4*)&Cb[gl*NDS + w4*NDSQ + 4*g] = make_float4(cv[4*g], cv[4*g+1], cv[4*g+2], cv[4*g+3]);
  }
  __syncthreads();
  if (tid < 64) {
    if constexpr (NDT == 4) {
      *(float4*)&dtb[((size_t)seq*LL + l0 + tid)*4] =
          make_float4(dts[tid*4], dts[tid*4+1], dts[tid*4+2], dts[tid*4+3]);
    } else {
      *(float2*)&dtb[((size_t)seq*LL + l0 + tid)*NDT] = make_float2(dts[tid*NDT], dts[tid*NDT+1]);
    }
  }
}

// ======= FUSED inproj + intra-chunk SSD v7 (cascade) — best measured (R4) =======
__global__ __launch_bounds__(256, 4) void k_inssd(
    const float* __restrict__ src, int srcMode,
    const float* __restrict__ in_w, const float* __restrict__ in_b,
    const float* __restrict__ conv_w, const float* __restrict__ conv_b,
    const float* __restrict__ dt_bias, const float* __restrict__ A_log,
    const float* __restrict__ Dp,
    float* __restrict__ zb, float* __restrict__ Cb,
    float* __restrict__ ybuf, float* __restrict__ states,
    float* __restrict__ cdec, float* __restrict__ acsOut)
{
  const int DIN = 16, NZ = 32, NDS = 64, DI = 32;
  const int NXBC = 160, NTOT = 196;
  __shared__ __align__(16) float sm[10240];  // 40960 B -> 4 blocks/CU
  float* Bt  = sm;            // [0,4096)     phase-1 write, phase-2 read
  float* Ct  = sm + 4096;     // [4096,8192)  phase 2
  float* xde = sm + 8192;     // [8192,10240) phase 2
  float* hp  = sm + 4096;     // [4096,4416)  phase-1 only (aliases Ct)
  float* ha  = sm + 4416;     // [4416,4448)  phase-1 only
  int tid = threadIdx.x;
  int cid = blockIdx.x & 63;
  int seq = blockIdx.x >> 6;
  int l0  = cid << 6;
  int lane = tid & 63;
  int w = __builtin_amdgcn_readfirstlane(tid >> 6);  // wave-uniform head index
  const float* sp; int sstr;
  if (srcMode == 0) { sp = src + (size_t)seq*LL*DIN; sstr = DIN; }
  else { sp = src + (size_t)(seq & 3)*LL*CCH + (seq >> 2)*16; sstr = CCH; }
  float xr2[DIN];
  {
    const float* p = sp + (size_t)(l0 + lane)*sstr;
#pragma unroll
    for (int k = 0; k < 4; ++k) {
      float4 v = *(const float4*)(p + 4*k);
      xr2[4*k+0]=v.x; xr2[4*k+1]=v.y; xr2[4*k+2]=v.z; xr2[4*k+3]=v.w;
    }
  }
  if (tid < 32) {
    int t = tid >> 4, d = tid & 15;
    int tok = l0 - 2 + t;
    ha[t*16 + d] = (tok >= 0) ? sp[(size_t)tok*sstr + d] : 0.f;
  }
  __syncthreads();
  // halo pre-products
  for (int i = tid; i < 2*NXBC; i += 256) {
    int t = i & 1, ch = i >> 1;
    const float* wr = in_w + (size_t)(NZ + ch)*DIN;
    const float* hr = &ha[t*16];
    float4 w0 = *(const float4*)(wr),    w1 = *(const float4*)(wr+4);
    float4 w2 = *(const float4*)(wr+8),  w3 = *(const float4*)(wr+12);
    float4 h0 = *(const float4*)(hr),    h1 = *(const float4*)(hr+4);
    float4 h2 = *(const float4*)(hr+8),  h3 = *(const float4*)(hr+12);
    float acc = h0.x*w0.x + h0.y*w0.y + h0.z*w0.z + h0.w*w0.w
              + h1.x*w1.x + h1.y*w1.y + h1.z*w1.z + h1.w*w1.w
              + h2.x*w2.x + h2.y*w2.y + h2.z*w2.z + h2.w*w2.w
              + h3.x*w3.x + h3.y*w3.y + h3.z*w3.z + h3.w*w3.w;
    hp[ch*2 + t] = acc;
  }
  __syncthreads();
  // scalar-pipe weight dot (wave-uniform row -> s_load)
  auto dot16 = [&](int row) -> float {
    const float* wr = in_w + (size_t)row*DIN;
    float4 w0 = *(const float4*)(wr),    w1 = *(const float4*)(wr+4);
    float4 w2 = *(const float4*)(wr+8),  w3 = *(const float4*)(wr+12);
    return xr2[0]*w0.x  + xr2[1]*w0.y  + xr2[2]*w0.z  + xr2[3]*w0.w
         + xr2[4]*w1.x  + xr2[5]*w1.y  + xr2[6]*w1.z  + xr2[7]*w1.w
         + xr2[8]*w2.x  + xr2[9]*w2.y  + xr2[10]*w2.z + xr2[11]*w2.w
         + xr2[12]*w3.x + xr2[13]*w3.y + xr2[14]*w3.z + xr2[15]*w3.w;
  };
  size_t gl = (size_t)seq*LL + l0 + lane;
  int tok = l0 + lane;
  float v0ok = (tok >= 2) ? 1.f : 0.f;
  float v1ok = (tok >= 1) ? 1.f : 0.f;
  {
    float zv[8];
#pragma unroll
    for (int j = 0; j < 8; ++j) {
      int row = w*8 + j;
      zv[j] = in_b[row] + dot16(row);
    }
    *(float4*)&zb[gl*NZ + w*8 + 0] = make_float4(zv[0], zv[1], zv[2], zv[3]);
    *(float4*)&zb[gl*NZ + w*8 + 4] = make_float4(zv[4], zv[5], zv[6], zv[7]);
  }
  float dtv;
  {
    int row = NTOT - 4 + w;
    dtv = softplusf(in_b[row] + dt_bias[w] + dot16(row));
  }
  auto convch = [&](int ch) -> float {
    int row = NZ + ch;
    float pm = dot16(row);
    float m1 = __shfl_up(pm, 1, 64);
    float m2 = __shfl_up(pm, 2, 64);
    float2 h01 = *(const float2*)&hp[ch*2];
    if (lane == 0) m1 = h01.y;
    m2 = (lane == 0) ? h01.x : ((lane == 1) ? h01.y : m2);
    float ib = in_b[row];
    float conv = conv_b[ch] + (m2+ib)*v0ok*conv_w[ch*3+0] + (m1+ib)*v1ok*conv_w[ch*3+1]
               + (pm+ib)*conv_w[ch*3+2];
    return siluf(conv);
  };
  // xs head w: registers only
  float xv[8];
#pragma unroll
  for (int j = 0; j < 8; ++j) xv[j] = convch(w*8 + j);
  // B conv channels -> Bt (disjoint from phase-1 aliases)
#pragma unroll
  for (int j = 0; j < 16; ++j) {
    int n = w*16 + j;
    Bt[swz(n, lane)] = convch(NZ + n);
  }
  // C conv channels: regs across the phase barrier (Ct aliases hp/ha)
  float cv[16];
#pragma unroll
  for (int j = 0; j < 16; ++j) cv[j] = convch(NZ + NDS + w*16 + j);
#pragma unroll
  for (int g = 0; g < 4; ++g)
    *(float4*)&Cb[gl*NDS + w*16 + 4*g] = make_float4(cv[4*g], cv[4*g+1], cv[4*g+2], cv[4*g+3]);
  // A-cumsum (register/shuffle only)
  float Aval = -__expf(A_log[w]);
  float Dh = Dp[w];
  float v = dtv * Aval;
#pragma unroll
  for (int off = 1; off < 64; off <<= 1) {
    float t = __shfl_up(v, off, 64);
    if (lane >= off) v += t;
  }
  float acs_l = v;
  float m = __shfl(v, 31, 64);
  float acsLast = __shfl(v, 63, 64);
  float el = __expf(fminf(acs_l - m, 60.f));
  float fl = __expf(fminf(m - acs_l, 60.f));
  __syncthreads();   // === phase barrier: hp/ha reads done ===
#pragma unroll
  for (int j = 0; j < 16; ++j) Ct[swz(w*16 + j, lane)] = cv[j];
  {
    float s1 = dtv*fl;
    float* xe = &xde[(w*64 + lane)*8];
    *(float4*)xe     = make_float4(xv[0]*s1, xv[1]*s1, xv[2]*s1, xv[3]*s1);
    *(float4*)(xe+4) = make_float4(xv[4]*s1, xv[5]*s1, xv[6]*s1, xv[7]*s1);
  }
  __syncthreads();
  int lt = (tid >> 4) << 2, st = (tid & 15) << 2;
  float acc[4][4] = {};
#pragma unroll 4
  for (int n = 0; n < 64; ++n) {
    float4 cvv = *(const float4*)&Ct[swz(n, lt)];
    float4 bvv = *(const float4*)&Bt[swz(n, st)];
    float cc[4] = {cvv.x, cvv.y, cvv.z, cvv.w};
    float bb[4] = {bvv.x, bvv.y, bvv.z, bvv.w};
#pragma unroll
    for (int i2 = 0; i2 < 4; ++i2)
#pragma unroll
      for (int j2 = 0; j2 < 4; ++j2)
        acc[i2][j2] += cc[i2]*bb[j2];
  }
  __syncthreads();
#pragma unroll
  for (int j = 0; j < 4; ++j) {
    *(float4*)&Ct[swz(st + j, lt)] = make_float4(acc[0][j], acc[1][j], acc[2][j], acc[3][j]);
  }
  __syncthreads();
  // ---- merged Yd + states: xde rows via broadcast b128; B via float4/4-tokens ----
  int lg = lane >> 2, lm = lane & 3;
  float ya[8] = {0,0,0,0,0,0,0,0};
  float sa[8] = {0,0,0,0,0,0,0,0};
#pragma unroll 2
  for (int s4 = 0; s4 < 64; s4 += 4) {
    float4 b4 = *(const float4*)&Bt[swz(lane, s4)];   // tokens s4..s4+3, channel=lane
    float bb[4] = {b4.x, b4.y, b4.z, b4.w};
#pragma unroll
    for (int u = 0; u < 4; ++u) {
      int s = s4 + u;
      float g = Ct[(s << 6) + (((lg ^ ((s >> 2) & 15))) << 2 | lm)];
      g = (s <= lane) ? g : 0.f;
      float b = bb[u];
      const float* xr = &xde[(w*64 + s)*8];
      float4 a0 = *(const float4*)xr, a1 = *(const float4*)(xr + 4);
      ya[0] += g*a0.x; ya[1] += g*a0.y; ya[2] += g*a0.z; ya[3] += g*a0.w;
      ya[4] += g*a1.x; ya[5] += g*a1.y; ya[6] += g*a1.z; ya[7] += g*a1.w;
      sa[0] += b*a0.x; sa[1] += b*a0.y; sa[2] += b*a0.z; sa[3] += b*a0.w;
      sa[4] += b*a1.x; sa[5] += b*a1.y; sa[6] += b*a1.z; sa[7] += b*a1.w;
    }
  }
  float* yp = &ybuf[gl*DI + w*8];
  *(float4*)yp     = make_float4(ya[0]*el + Dh*xv[0], ya[1]*el + Dh*xv[1],
                                 ya[2]*el + Dh*xv[2], ya[3]*el + Dh*xv[3]);
  *(float4*)(yp+4) = make_float4(ya[4]*el + Dh*xv[4], ya[5]*el + Dh*xv[5],
                                 ya[6]*el + Dh*xv[6], ya[7]*el + Dh*xv[7]);
  {
    float r2 = __expf(acsLast - m);
    float* sp2 = &states[(((size_t)seq*4 + w)*NCHK + cid)*(size_t)(8*NDS) + lane*8];
    *(float4*)sp2     = make_float4(sa[0]*r2, sa[1]*r2, sa[2]*r2, sa[3]*r2);
    *(float4*)(sp2+4) = make_float4(sa[4]*r2, sa[5]*r2, sa[6]*r2, sa[7]*r2);
  }
  if (lane == 63) cdec[((size_t)seq*4 + w)*NCHK + cid] = __expf(acsLast);
  acsOut[((size_t)seq*4 + w)*LL + l0 + lane] = acs_l;
}

// ---------------- SSD intra-chunk v4 (seed path) ----------------
template<int DS, int NH>
__global__ __launch_bounds__(256) void k_ssd1(
    const float* __restrict__ xs, const float* __restrict__ dtb,
    const float* __restrict__ Bb, const float* __restrict__ Cb,
    const float* __restrict__ A_log, const float* __restrict__ Dp,
    float* __restrict__ ybuf, float* __restrict__ states,
    float* __restrict__ cdec, float* __restrict__ acsOut)
{
  constexpr int DI = NH*8;
  constexpr int NG = DS/4;
  __shared__ __align__(16) float BtBl[DS*64];
  __shared__ __align__(16) float CtGt[64*64];
  __shared__ __align__(16) float xde[NH*64*8];
  int tid = threadIdx.x;
  int cid = blockIdx.x & 63;
  int seq = blockIdx.x >> 6;
  int l0  = cid << 6;
  for (int i = tid; i < 16*DS; i += 256) {
    int ng = i % NG, l = i / NG;
    size_t g = ((size_t)seq*LL + l0 + l)*DS + 4*ng;
    float4 bv = *(const float4*)&Bb[g];
    float4 cv = *(const float4*)&Cb[g];
    BtBl[swz(4*ng+0, l)] = bv.x; BtBl[swz(4*ng+1, l)] = bv.y;
    BtBl[swz(4*ng+2, l)] = bv.z; BtBl[swz(4*ng+3, l)] = bv.w;
    CtGt[swz(4*ng+0, l)] = cv.x; CtGt[swz(4*ng+1, l)] = cv.y;
    CtGt[swz(4*ng+2, l)] = cv.z; CtGt[swz(4*ng+3, l)] = cv.w;
  }
  __syncthreads();
  int lt = (tid >> 4) << 2, st = (tid & 15) << 2;
  float acc[4][4] = {};
#pragma unroll 4
  for (int n = 0; n < DS; ++n) {
    float4 cv = *(const float4*)&CtGt[swz(n, lt)];
    float4 bv = *(const float4*)&BtBl[swz(n, st)];
    float cc[4] = {cv.x, cv.y, cv.z, cv.w};
    float bb[4] = {bv.x, bv.y, bv.z, bv.w};
#pragma unroll
    for (int i2 = 0; i2 < 4; ++i2)
#pragma unroll
      for (int j2 = 0; j2 < 4; ++j2)
        acc[i2][j2] += cc[i2]*bb[j2];
  }
  __syncthreads();
#pragma unroll
  for (int j = 0; j < 4; ++j) {
    float4 gv = make_float4(acc[0][j], acc[1][j], acc[2][j], acc[3][j]);
    *(float4*)&CtGt[swz(st + j, lt)] = gv;
  }
  for (int i = tid; i < 16*DS; i += 256) {
    int ng = i % NG, l = i / NG;
    float4 bv = *(const float4*)&Bb[((size_t)seq*LL + l0 + l)*DS + 4*ng];
    *(float4*)&BtBl[l*DS + 4*ng] = bv;
  }
  __syncthreads();
  int w = tid >> 6, lane = tid & 63;
  if (w < NH) {
    int h = w;
    float dt_l = dtb[((size_t)seq*LL + l0 + lane)*NH + h];
    float Aval = -__expf(A_log[h]);
    float Dh = Dp[h];
    float v = dt_l * Aval;
#pragma unroll
    for (int off = 1; off < 64; off <<= 1) {
      float t = __shfl_up(v, off, 64);
      if (lane >= off) v += t;
    }
    float acs_l = v;
    float m = __shfl(v, 31, 64);
    float acsLast = __shfl(v, 63, 64);
    float el = __expf(fminf(acs_l - m, 60.f));
    float fl = __expf(fminf(m - acs_l, 60.f));
    const float* xp = &xs[((size_t)seq*LL + l0 + lane)*DI + h*8];
    float4 x0 = *(const float4*)xp, x1 = *(const float4*)(xp + 4);
    float s1 = dt_l*fl;
    float* xe = &xde[(h*64 + lane)*8];
    *(float4*)xe     = make_float4(x0.x*s1, x0.y*s1, x0.z*s1, x0.w*s1);
    *(float4*)(xe+4) = make_float4(x1.x*s1, x1.y*s1, x1.z*s1, x1.w*s1);
    int lg = lane >> 2, lm = lane & 3;
    float ya[8] = {0,0,0,0,0,0,0,0};
#pragma unroll 4
    for (int s = 0; s < 64; ++s) {
      float g = CtGt[(s << 6) + ((((lg ^ ((s >> 2) & 15))) << 2) | lm)];
      g = (s <= lane) ? g : 0.f;
      const float* xr = &xde[(h*64 + s)*8];
      float4 a0 = *(const float4*)xr, a1 = *(const float4*)(xr + 4);
      ya[0] += g*a0.x; ya[1] += g*a0.y; ya[2] += g*a0.z; ya[3] += g*a0.w;
      ya[4] += g*a1.x; ya[5] += g*a1.y; ya[6] += g*a1.z; ya[7] += g*a1.w;
    }
    float* yp = &ybuf[((size_t)seq*LL + l0 + lane)*DI + h*8];
    *(float4*)yp     = make_float4(ya[0]*el + Dh*x0.x, ya[1]*el + Dh*x0.y,
                                   ya[2]*el + Dh*x0.z, ya[3]*el + Dh*x0.w);
    *(float4*)(yp+4) = make_float4(ya[4]*el + Dh*x1.x, ya[5]*el + Dh*x1.y,
                                   ya[6]*el + Dh*x1.z, ya[7]*el + Dh*x1.w);
    if (lane < DS) {
      float r2 = __expf(acsLast - m);
      float sa[8] = {0,0,0,0,0,0,0,0};
#pragma unroll 4
      for (int ll = 0; ll < 64; ++ll) {
        float b = BtBl[ll*DS + lane];
        const float* xr = &xde[(h*64 + ll)*8];
        float4 a0 = *(const float4*)xr, a1 = *(const float4*)(xr + 4);
        sa[0] += b*a0.x; sa[1] += b*a0.y; sa[2] += b*a0.z; sa[3] += b*a0.w;
        sa[4] += b*a1.x; sa[5] += b*a1.y; sa[6] += b*a1.z; sa[7] += b*a1.w;
      }
      float* sp2 = &states[(((size_t)seq*NH + h)*NCHK + cid)*(size_t)(8*DS) + lane*8];
      *(float4*)sp2     = make_float4(sa[0]*r2, sa[1]*r2, sa[2]*r2, sa[3]*r2);
      *(float4*)(sp2+4) = make_float4(sa[4]*r2, sa[5]*r2, sa[6]*r2, sa[7]*r2);
    }
    if (lane == 63) cdec[((size_t)seq*NH + h)*NCHK + cid] = __expf(acsLast);
    acsOut[((size_t)seq*NH + h)*LL + l0 + lane] = acs_l;
  }
}

// ---------------- inter-chunk scan (+ optional 512-float zero task) ----------------
__global__ __launch_bounds__(512) void k_scan(float* __restrict__ st, const float* __restrict__ cd,
                                              int PN, float* __restrict__ zbuf)
{
  int tid = threadIdx.x;
  if (zbuf && blockIdx.x == 0 && tid < 512) zbuf[tid] = 0.f;
  size_t base = (size_t)blockIdx.x * NCHK * PN + tid;
  const float* c = cd + (size_t)blockIdx.x * NCHK;
  float carry = 0.f;
  for (int k = 0; k < NCHK; ++k) {
    size_t a = base + (size_t)k*PN;
    float s = st[a];
    st[a] = carry;
    carry = carry*c[k] + s;
  }
}

// ======= FUSED Yo + gating + RMSNorm + out-proj v4 =======
// v4: gt back to DIP layout (gt2 b32 rewrite regressed, R5); pre-barrier register
//     prefetch of ybuf/zb/acsG/res (latency-bound kernel: overlap input HBM latency
//     with LDS staging); pvs/ow staging vectorized to float4.
template<int DS, int NH, int DOUT>
__global__ __launch_bounds__(256, 4) void k_yogate(
    const float* __restrict__ ybuf, const float* __restrict__ Cb,
    const float* __restrict__ prevSt, const float* __restrict__ acsG,
    const float* __restrict__ zb,
    const float* __restrict__ rms_w, const float* __restrict__ out_w,
    float* __restrict__ dst, int resMode, const float* __restrict__ res,
    const float* __restrict__ skipPtr, float* __restrict__ gmAcc)
{
  constexpr int DI = NH*8;
  constexpr int NG = DS/4;
  constexpr int DIP = DI + 4;
  constexpr int OQ = DOUT/4;
  __shared__ __align__(16) float Ct2[DS*64];
  __shared__ __align__(16) float pvs[NH*DS*8];
  __shared__ __align__(16) float gt[64*DIP];
  __shared__ float ps[NH*64];
  __shared__ __align__(16) float ow[DOUT*DI];
  __shared__ float rwl[DI];
  int tid = threadIdx.x;
  int cid = blockIdx.x & 63;
  int seq = blockIdx.x >> 6;
  int l0  = cid << 6;
  int lane = tid & 63, w = tid >> 6;
  // ---- early input prefetch: pure-global inputs consumed after the barrier.
  //      Issued BEFORE staging so their HBM latency hides under it. ----
  float4 y0, y1, z0, z1;
  float acs_raw = 0.f;
  if (w < NH) {
    size_t gi = ((size_t)seq*LL + l0 + lane)*DI + w*8;
    acs_raw = acsG[((size_t)seq*NH + w)*LL + l0 + lane];
    y0 = *(const float4*)&ybuf[gi]; y1 = *(const float4*)&ybuf[gi+4];
    z0 = *(const float4*)&zb[gi];   z1 = *(const float4*)&zb[gi+4];
  }
  float rv[OQ];
  {
    int l = l0 + lane;
    const float* rp = nullptr; float skip = 1.f;
    if (resMode == 1) rp = res + ((size_t)seq*LL + l)*DOUT + w*OQ;
    else if (resMode == 2) {
      int s = seq / B_, b = seq % B_;
      rp = res + ((size_t)b*LL + l)*CCH + s*DOUT + w*OQ;
      skip = skipPtr[0];
    }
#pragma unroll
    for (int j = 0; j < OQ; ++j) rv[j] = rp ? skip * rp[j] : 0.f;
  }
  // ---- LDS staging ----
  for (int i = tid; i < 16*DS; i += 256) {
    int ng = i % NG, l = i / NG;
    float4 cv = *(const float4*)&Cb[((size_t)seq*LL + l0 + l)*DS + 4*ng];
    Ct2[swz(4*ng+0, l)] = cv.x; Ct2[swz(4*ng+1, l)] = cv.y;
    Ct2[swz(4*ng+2, l)] = cv.z; Ct2[swz(4*ng+3, l)] = cv.w;
  }
  for (int i = tid; i < NH*DS*2; i += 256) {
    int h = i / (DS*2), o4 = i % (DS*2);
    float4 pv = *(const float4*)&prevSt[(((size_t)seq*NH + h)*NCHK + cid)*(size_t)(DS*8) + o4*4];
    *(float4*)&pvs[h*DS*8 + o4*4] = pv;
  }
  for (int i = tid; i < DOUT*DI/4; i += 256)
    *(float4*)&ow[i*4] = *(const float4*)&out_w[i*4];
  for (int i = tid; i < DI; i += 256) rwl[i] = rms_w[i];
  __syncthreads();
  if (w < NH) {
    float el = __expf(acs_raw);
    int lg = lane >> 2, lm = lane & 3;
    float acc[8] = {0,0,0,0,0,0,0,0};
#pragma unroll 4
    for (int n = 0; n < DS; ++n) {
      float c = Ct2[(n << 6) + ((((lg ^ ((n >> 2) & 15))) << 2) | lm)];
      const float* pr = &pvs[(w*DS + n)*8];
      float4 p0 = *(const float4*)pr, p1 = *(const float4*)(pr + 4);
      acc[0] += c*p0.x; acc[1] += c*p0.y; acc[2] += c*p0.z; acc[3] += c*p0.w;
      acc[4] += c*p1.x; acc[5] += c*p1.y; acc[6] += c*p1.z; acc[7] += c*p1.w;
    }
    float g[8];
    g[0] = (y0.x + el*acc[0]) * siluf(z0.x);
    g[1] = (y0.y + el*acc[1]) * siluf(z0.y);
    g[2] = (y0.z + el*acc[2]) * siluf(z0.z);
    g[3] = (y0.w + el*acc[3]) * siluf(z0.w);
    g[4] = (y1.x + el*acc[4]) * siluf(z1.x);
    g[5] = (y1.y + el*acc[5]) * siluf(z1.y);
    g[6] = (y1.z + el*acc[6]) * siluf(z1.z);
    g[7] = (y1.w + el*acc[7]) * siluf(z1.w);
    float ssum = 0.f;
#pragma unroll
    for (int j = 0; j < 8; ++j) ssum += g[j]*g[j];
    float* gp = &gt[lane*DIP + w*8];
    *(float4*)gp     = make_float4(g[0], g[1], g[2], g[3]);
    *(float4*)(gp+4) = make_float4(g[4], g[5], g[6], g[7]);
    ps[w*64 + lane] = ssum;
  }
  __syncthreads();
  int tok = lane, q = w;
  float rsum = 0.f;
#pragma unroll
  for (int h = 0; h < NH; ++h) rsum += ps[h*64 + tok];
  float r = rsqrtf(rsum*(1.f/DI) + 1e-5f);
  float gr[DI];
#pragma unroll
  for (int k = 0; k < DI/4; ++k) {
    float4 v = *(const float4*)&gt[tok*DIP + 4*k];
    gr[4*k+0] = v.x*r*rwl[4*k+0];
    gr[4*k+1] = v.y*r*rwl[4*k+1];
    gr[4*k+2] = v.z*r*rwl[4*k+2];
    gr[4*k+3] = v.w*r*rwl[4*k+3];
  }
  int l = l0 + tok;
  float ov[OQ];
#pragma unroll
  for (int j = 0; j < OQ; ++j) {
    int o = q*OQ + j;
    const float* wr = &ow[o*DI];
    float acc2 = rv[j];
#pragma unroll
    for (int k = 0; k < DI/4; ++k) {
      float4 wv = *(const float4*)(wr + 4*k);
      acc2 += gr[4*k]*wv.x + gr[4*k+1]*wv.y + gr[4*k+2]*wv.z + gr[4*k+3]*wv.w;
    }
    ov[j] = acc2;
  }
  float* dp = &dst[((size_t)seq*LL + l)*DOUT + q*OQ];
  if constexpr (OQ == 4) *(float4*)dp = make_float4(ov[0], ov[1], ov[2], ov[3]);
  else *(float2*)dp = make_float2(ov[0], ov[1]);
  // fused gm partial sums (layer-1 only)
  if (gmAcc) {
#pragma unroll
    for (int j = 0; j < OQ; ++j) {
      float sv = ov[j];
#pragma unroll
      for (int off = 32; off > 0; off >>= 1) sv += __shfl_down(sv, off, 64);
      if (tok == 0) atomicAdd(&gmAcc[(size_t)seq*DOUT + q*OQ + j], sv);
    }
  }
}

// ---------------- LN over C of x[b,c,l] -> xn[b,l,c] ----------------
__global__ __launch_bounds__(256) void k_ln1(const float* __restrict__ x,
    const float* __restrict__ w, const float* __restrict__ bb, float* __restrict__ xn)
{
  __shared__ float tile[128*65];
  __shared__ float mu[64], rs[64];
  int tid = threadIdx.x;
  int b = blockIdx.x >> 6;
  int l0 = (blockIdx.x & 63) << 6;
  for (int i = tid; i < 8192; i += 256) {
    int l = i & 63, c = i >> 6;
    tile[c*65 + l] = x[((size_t)b*CCH + c)*LL + l0 + l];
  }
  __syncthreads();
  if (tid < 64) {
    float s = 0.f;
    for (int c = 0; c < CCH; ++c) s += tile[c*65 + tid];
    float m = s * (1.f/CCH);
    float v = 0.f;
    for (int c = 0; c < CCH; ++c) { float d = tile[c*65 + tid] - m; v += d*d; }
    mu[tid] = m; rs[tid] = rsqrtf(v*(1.f/CCH) + 1e-5f);
  }
  __syncthreads();
  for (int i = tid; i < 8192; i += 256) {
    int c = i & 127, l = i >> 7;
    xn[((size_t)b*LL + l0 + l)*CCH + c] = (tile[c*65 + l] - mu[l])*rs[l]*w[c] + bb[c];
  }
}

// ---------------- gmix (gm buffer holds SUMS; scale by 1/LL here) ----------------
__global__ __launch_bounds__(256) void k_mix(const float* __restrict__ gm,
    const float* __restrict__ crossW, float* __restrict__ gmix)
{
  __shared__ float wsm[64];
  int tid = threadIdx.x;
  if (tid < 8) {
    float mx = -1e30f;
    for (int p = 0; p < 8; ++p) mx = fmaxf(mx, crossW[tid*8 + p]);
    float e[8]; float s = 0.f;
    for (int p = 0; p < 8; ++p) { e[p] = __expf(crossW[tid*8 + p] - mx); s += e[p]; }
    for (int p = 0; p < 8; ++p) wsm[tid*8 + p] = e[p] / s;
  }
  __syncthreads();
  for (int i = tid; i < 512; i += 256) {
    int c = i & 15; int bb = (i >> 4) & 3; int p = i >> 6;
    float acc = 0.f;
    for (int q = 0; q < 8; ++q)
      acc += gm[((size_t)(q*B_ + bb))*16 + c] * (1.f/LL) * wsm[q*8 + p];
    gmix[((size_t)(p*B_ + bb))*16 + c] = acc;
  }
}

// ---------------- assemble ys+gmix, LN2, + (x + detok(gf2)) -> outb[b,c,l] ----------------
__global__ __launch_bounds__(256) void k_out2(const float* __restrict__ ys,
    const float* __restrict__ gmix, const float* __restrict__ w, const float* __restrict__ bb,
    const float* __restrict__ x, const float* __restrict__ gf2,
    const float* __restrict__ dw, const float* __restrict__ db,
    float* __restrict__ outb)
{
  __shared__ float tile[128*65];
  __shared__ float mu[64], rs[64];
  int tid = threadIdx.x;
  int b = blockIdx.x >> 6;
  int l0 = (blockIdx.x & 63) << 6;
  for (int i = tid; i < 8192; i += 256) {
    int c = i & 15; int l = (i >> 4) & 63; int s = i >> 10;
    int seq = s*B_ + b;
    tile[(s*16 + c)*65 + l] = ys[((size_t)seq*LL + l0 + l)*16 + c] + gmix[(size_t)seq*16 + c];
  }
  __syncthreads();
  if (tid < 64) {
    float sm = 0.f;
    for (int c = 0; c < 128; ++c) sm += tile[c*65 + tid];
    float m = sm * (1.f/128.f);
    float v = 0.f;
    for (int c = 0; c < 128; ++c) { float d = tile[c*65 + tid] - m; v += d*d; }
    mu[tid] = m; rs[tid] = rsqrtf(v*(1.f/128.f) + 1e-5f);
  }
  __syncthreads();
  int lfix = tid & 63;
  float g8[8];
  {
    const float* gp = gf2 + ((size_t)b*LL + l0 + lfix)*8;
#pragma unroll
    for (int k = 0; k < 8; ++k) g8[k] = gp[k];
  }
  for (int i = tid; i < 8192; i += 256) {
    int l = i & 63, c = i >> 6;
    size_t gi = ((size_t)b*CCH + c)*LL + l0 + l;
    float det = db[c];
#pragma unroll
    for (int k = 0; k < 8; ++k) det += g8[k]*dw[c*8 + k];
    outb[gi] = (tile[c*65 + l] - mu[l])*rs[l]*w[c] + bb[c] + x[gi] + det;
  }
}

// ---------------- fc1: register-tiled GEMM, transposed weight tile ----------------
__global__ __launch_bounds__(256) void k_fc1(const float* __restrict__ src,
    const float* __restrict__ w, const float* __restrict__ bias, float* __restrict__ dst)
{
  constexpr int WTP = 68;
  __shared__ float st[128*64];
  __shared__ __align__(16) float wtT[128*WTP];
  int tid = threadIdx.x;
  int blk = blockIdx.x;
  int ot = blk & 3;
  int lt = (blk >> 2) & 63;
  int b  = blk >> 8;
  int l0 = lt << 6, o0 = ot << 6;
  for (int i = tid; i < 8192; i += 256) {
    int l = i & 63, c = i >> 6;
    st[c*64 + l] = src[((size_t)b*CCH + c)*LL + l0 + l];
  }
  for (int i = tid; i < 8192; i += 256) {
    int c = i & 127, o = i >> 7;
    wtT[c*WTP + o] = w[(size_t)(o0 + o)*128 + c];
  }
  __syncthreads();
  int l4 = (tid & 15) << 2, o4 = (tid >> 4) << 2;
  float a0[4] = {}, a1[4] = {}, a2[4] = {}, a3[4] = {};
#pragma unroll 4
  for (int c = 0; c < 128; ++c) {
    float4 sv = *(float4*)&st[c*64 + l4];
    float4 wv = *(float4*)&wtT[c*WTP + o4];
    a0[0] += wv.x*sv.x; a0[1] += wv.x*sv.y; a0[2] += wv.x*sv.z; a0[3] += wv.x*sv.w;
    a1[0] += wv.y*sv.x; a1[1] += wv.y*sv.y; a1[2] += wv.y*sv.z; a1[3] += wv.y*sv.w;
    a2[0] += wv.z*sv.x; a2[1] += wv.z*sv.y; a2[2] += wv.z*sv.z; a2[3] += wv.z*sv.w;
    a3[0] += wv.w*sv.x; a3[1] += wv.w*sv.y; a3[2] += wv.w*sv.z; a3[3] += wv.w*sv.w;
  }
  float* rows[4] = {a0, a1, a2, a3};
#pragma unroll
  for (int j = 0; j < 4; ++j) {
    int o = o0 + o4 + j;
    float bi = bias[o];
    float* a = rows[j];
    *(float4*)&dst[((size_t)b*256 + o)*LL + l0 + l4] =
        make_float4(a[0]+bi, a[1]+bi, a[2]+bi, a[3]+bi);
  }
}

// ---------------- depthwise 3x3 + gelu, LDS-tiled ----------------
__global__ __launch_bounds__(256) void k_dw(const float* __restrict__ h1,
    const float* __restrict__ w, const float* __restrict__ bias, float* __restrict__ h2)
{
  __shared__ float tile[66*66];
  int tid = threadIdx.x;
  int blk = blockIdx.x;
  const float* base = h1 + (size_t)blk*LL;
  const float* wp = w + (blk & 255)*9;
  float bi = bias[blk & 255];
  for (int i = tid; i < 66*66; i += 256) {
    int r = i / 66, cc = i % 66;
    int gr = r - 1, gc = cc - 1;
    tile[i] = (gr >= 0 && gr < HH && gc >= 0 && gc < WW) ? base[gr*WW + gc] : 0.f;
  }
  float w00 = wp[0], w01 = wp[1], w02 = wp[2];
  float w10 = wp[3], w11 = wp[4], w12 = wp[5];
  float w20 = wp[6], w21 = wp[7], w22 = wp[8];
  __syncthreads();
  float* outp = h2 + (size_t)blk*LL;
#pragma unroll
  for (int k = 0; k < 16; ++k) {
    int j = tid + k*256;
    int row = j >> 6, col = j & 63;
    const float* t0 = &tile[row*66 + col];
    float acc = t0[0]*w00  + t0[1]*w01  + t0[2]*w02
              + t0[66]*w10 + t0[67]*w11 + t0[68]*w12
              + t0[132]*w20 + t0[133]*w21 + t0[134]*w22;
    float v = acc + bi;
    float u = 0.7978845608028654f*(v + 0.044715f*v*v*v);
    float e = __expf(2.f*u);
    float th = 1.f - 2.f/(e + 1.f);
    outp[j] = 0.5f*v*(1.f + th);
  }
}

// ---------------- fc2: register-tiled GEMM, transposed weight tile ----------------
__global__ __launch_bounds__(256) void k_fc2(const float* __restrict__ h2,
    const float* __restrict__ w, const float* __restrict__ bias,
    const float* __restrict__ resid, float* __restrict__ dst)
{
  constexpr int WTP = 36;
  __shared__ float st[128*64];
  __shared__ __align__(16) float wtT[256*WTP];
  int tid = threadIdx.x;
  int blk = blockIdx.x;
  int ct = blk & 3;
  int lt = (blk >> 2) & 63;
  int b  = blk >> 8;
  int l0 = lt << 6, c0 = ct << 5;
  for (int i = tid; i < 32*256; i += 256) {
    int o = i & 255, c = i >> 8;
    wtT[o*WTP + c] = w[(size_t)(c0 + c)*256 + o];
  }
  int l4 = (tid & 15) << 2, c2 = (tid >> 4) << 1;
  float a0[4] = {}, a1[4] = {};
  for (int ko = 0; ko < 256; ko += 128) {
    __syncthreads();
    for (int i = tid; i < 8192; i += 256) {
      int l = i & 63, o = i >> 6;
      st[o*64 + l] = h2[((size_t)b*256 + ko + o)*LL + l0 + l];
    }
    __syncthreads();
#pragma unroll 4
    for (int o = 0; o < 128; ++o) {
      float4 sv = *(float4*)&st[o*64 + l4];
      float2 wv = *(float2*)&wtT[(ko + o)*WTP + c2];
      a0[0] += wv.x*sv.x; a0[1] += wv.x*sv.y; a0[2] += wv.x*sv.z; a0[3] += wv.x*sv.w;
      a1[0] += wv.y*sv.x; a1[1] += wv.y*sv.y; a1[2] += wv.y*sv.z; a1[3] += wv.y*sv.w;
    }
  }
  float* rows[2] = {a0, a1};
#pragma unroll
  for (int j = 0; j < 2; ++j) {
    int c = c0 + c2 + j;
    float bi = bias[c];
    size_t gi = ((size_t)b*CCH + c)*LL + l0 + l4;
    float4 rv = *(const float4*)&resid[gi];
    float* a = rows[j];
    *(float4*)&dst[gi] = make_float4(a[0]+bi+rv.x, a[1]+bi+rv.y, a[2]+bi+rv.z, a[3]+bi+rv.w);
  }
}

extern "C" void kernel_launch(void* const* d_in, const int* in_sizes, int n_in,
                              void* d_out, int out_size, void* d_ws, size_t ws_size,
                              hipStream_t stream) {
  (void)in_sizes; (void)n_in; (void)out_size; (void)ws_size;
  const float* x        = (const float*)d_in[0];
  const float* tok_w    = (const float*)d_in[1];
  const float* tok_b    = (const float*)d_in[2];
  const float* detok_w  = (const float*)d_in[3];
  const float* detok_b  = (const float*)d_in[4];
  const float* sm_in_w  = (const float*)d_in[5];
  const float* sm_in_b  = (const float*)d_in[6];
  const float* sm_conv_w= (const float*)d_in[7];
  const float* sm_conv_b= (const float*)d_in[8];
  const float* sm_A_log = (const float*)d_in[9];
  const float* sm_D     = (const float*)d_in[10];
  const float* sm_dt_b  = (const float*)d_in[11];
  const float* sm_rms_w = (const float*)d_in[12];
  const float* sm_out_w = (const float*)d_in[13];
  const float* cm_in_w  = (const float*)d_in[14];
  const float* cm_in_b  = (const float*)d_in[15];
  const float* cm_conv_w= (const float*)d_in[16];
  const float* cm_conv_b= (const float*)d_in[17];
  const float* cm_A_log = (const float*)d_in[18];
  const float* cm_D     = (const float*)d_in[19];
  const float* cm_dt_b  = (const float*)d_in[20];
  const float* cm_rms_w = (const float*)d_in[21];
  const float* cm_out_w = (const float*)d_in[22];
  const float* cross_W  = (const float*)d_in[23];
  const float* n1w      = (const float*)d_in[24];
  const float* n1b      = (const float*)d_in[25];
  const float* n2w      = (const float*)d_in[26];
  const float* n2b      = (const float*)d_in[27];
  const float* fc1w     = (const float*)d_in[28];
  const float* fc1b     = (const float*)d_in[29];
  const float* dww      = (const float*)d_in[30];
  const float* dwb      = (const float*)d_in[31];
  const float* fc2w     = (const float*)d_in[32];
  const float* fc2b     = (const float*)d_in[33];
  const float* skp      = (const float*)d_in[34];
  float* ws  = (float*)d_ws;
  float* out = (float*)d_out;

  const size_t SGF0 = 0;
  const size_t SOUTn= 131072;
  const size_t XN   = 2097152;
  const size_t YS   = 4194304;
  const size_t OUTB = 6291456;
  const size_t GM   = 8388608;
  const size_t GMIX = 8389120;
  const size_t SCR  = 8389632;
  const size_t CZ   = SCR;
  const size_t CCF  = CZ   + 4194304;
  const size_t CACS = CCF  + 8388608;
  const size_t CST  = CACS + 2097152;
  const size_t CCD  = CST  + 4194304;
  const size_t CY   = CCD  + 8192;
  const size_t XB   = CY   + 4194304;
  const size_t SZ   = SCR;
  const size_t SDT  = SZ  + 262144;
  const size_t SXS  = SDT + 32768;
  const size_t SB   = SXS + 262144;
  const size_t SC   = SB  + 262144;
  const size_t SACS = SC  + 262144;
  const size_t SST  = SACS + 32768;
  const size_t SCD  = SST + 65536;
  const size_t SY   = SCD + 512;
  const size_t H1 = SCR;
  const size_t H2 = SCR + 4194304;

  // ===== seed path =====
  k_seedtok<<<B_*64, 256, 0, stream>>>(x, tok_w, tok_b, ws + SGF0);
  k_inproj<8,16,16,2><<<B_*64, 256, 0, stream>>>(ws + SGF0, 0, sm_in_w, sm_in_b, sm_conv_w,
      sm_conv_b, sm_dt_b, ws + SZ, ws + SDT, ws + SXS, ws + SB, ws + SC);
  k_ssd1<16,2><<<B_*NCHK, 256, 0, stream>>>(ws + SXS, ws + SDT, ws + SB, ws + SC,
      sm_A_log, sm_D, ws + SY, ws + SST, ws + SCD, ws + SACS);
  k_scan<<<B_*2, 128, 0, stream>>>(ws + SST, ws + SCD, 128, nullptr);
  k_yogate<16,2,8><<<B_*NCHK, 256, 0, stream>>>(ws + SY, ws + SC, ws + SST, ws + SACS,
      ws + SZ, sm_rms_w, sm_out_w, ws + SOUTn, 1, ws + SGF0, skp, nullptr);

  // ===== norm1 =====
  k_ln1<<<B_*64, 256, 0, stream>>>(x, n1w, n1b, ws + XN);

  // ===== cascade layer 0 =====
  k_inssd<<<32*NCHK, 256, 0, stream>>>(ws + XN, 1, cm_in_w, cm_in_b, cm_conv_w,
      cm_conv_b, cm_dt_b, cm_A_log, cm_D, ws + CZ, ws + CCF,
      ws + CY, ws + CST, ws + CCD, ws + CACS);
  k_scan<<<32*4, 512, 0, stream>>>(ws + CST, ws + CCD, 512, nullptr);
  k_yogate<64,4,16><<<32*NCHK, 256, 0, stream>>>(ws + CY, ws + CCF, ws + CST, ws + CACS,
      ws + CZ, cm_rms_w, cm_out_w, ws + XB, 0, nullptr, skp, nullptr);

  // ===== cascade layer 1 =====
  k_inssd<<<32*NCHK, 256, 0, stream>>>(ws + XB, 0, cm_in_w + 3136, cm_in_b + 196,
      cm_conv_w + 480, cm_conv_b + 160, cm_dt_b + 4, cm_A_log + 4, cm_D + 4, ws + CZ, ws + CCF,
      ws + CY, ws + CST, ws + CCD, ws + CACS);
  k_scan<<<32*4, 512, 0, stream>>>(ws + CST, ws + CCD, 512, ws + GM);  // also zeroes GM
  k_yogate<64,4,16><<<32*NCHK, 256, 0, stream>>>(ws + CY, ws + CCF, ws + CST, ws + CACS,
      ws + CZ, cm_rms_w + 32, cm_out_w + 512, ws + YS, 2, ws + XN, skp, ws + GM);

  // ===== cross mix + norm2 + (fused detok seed) =====
  k_mix<<<1, 256, 0, stream>>>(ws + GM, cross_W, ws + GMIX);
  k_out2<<<B_*64, 256, 0, stream>>>(ws + YS, ws + GMIX, n2w, n2b,
      x, ws + SOUTn, detok_w, detok_b, ws + OUTB);

  // ===== FFN =====
  k_fc1<<<B_*64*4, 256, 0, stream>>>(ws + OUTB, fc1w, fc1b, ws + H1);
  k_dw<<<B_*256, 256, 0, stream>>>(ws + H1, dww, dwb, ws + H2);
  k_fc2<<<B_*64*4, 256, 0, stream>>>(ws + H2, fc2w, fc2b, ws + OUTB, out);
}

// Round 7
// 457.266 us; speedup vs baseline: 1.1032x; 1.1032x over previous
//
#include <hip/hip_runtime.h>
#include <math.h>

#define B_ 4
#define CCH 128
#define HH 64
#define WW 64
#define LL 4096
#define NCHK 64

__device__ __forceinline__ float siluf(float x) { return x / (1.f + __expf(-x)); }
__device__ __forceinline__ float softplusf(float x) { return (x > 20.f) ? x : log1pf(__expf(x)); }
// swizzled [n][l] layout, pitch 64: phys = n*64 + (((l>>2) ^ ((n>>2)&15))<<2 | (l&3))
__device__ __forceinline__ int swz(int n, int l) {
  return (n << 6) + ((((l >> 2) ^ ((n >> 2) & 15)) << 2) | (l & 3));
}

// ---------------- seed tokenize v2 ----------------
__global__ __launch_bounds__(256) void k_seedtok(const float* __restrict__ x,
    const float* __restrict__ w, const float* __restrict__ bias, float* __restrict__ gf)
{
  __shared__ float tile[128*65];
  __shared__ float sw[8*128];
  __shared__ float bl[8];
  int tid = threadIdx.x;
  int b = blockIdx.x >> 6;
  int l0 = (blockIdx.x & 63) << 6;
  for (int i = tid; i < 1024; i += 256) sw[i] = w[i];
  if (tid < 8) bl[tid] = bias[tid];
  for (int i = tid; i < 8192; i += 256) {
    int l = i & 63, c = i >> 6;
    tile[c*65 + l] = x[((size_t)b*CCH + c)*LL + l0 + l];
  }
  __syncthreads();
  int l = tid & 63, q = tid >> 6;
  float a0 = bl[2*q], a1 = bl[2*q+1];
  const float* w0 = &sw[(2*q)*128];
  const float* w1 = &sw[(2*q+1)*128];
#pragma unroll 4
  for (int c = 0; c < 128; ++c) {
    float xv = tile[c*65 + l];
    a0 += xv * w0[c];
    a1 += xv * w1[c];
  }
  *(float2*)&gf[((size_t)b*LL + l0 + l)*8 + 2*q] = make_float2(a0, a1);
}

// ---------------- fused in-projection + conv3 + silu + softplus(dt) (seed path) ----------------
template<int DIN, int NZ, int NDS, int NDT>
__global__ __launch_bounds__(256) void k_inproj(
    const float* __restrict__ src, int srcMode,
    const float* __restrict__ in_w, const float* __restrict__ in_b,
    const float* __restrict__ conv_w, const float* __restrict__ conv_b,
    const float* __restrict__ dt_bias,
    float* __restrict__ zb, float* __restrict__ dtb,
    float* __restrict__ xsb, float* __restrict__ Bb, float* __restrict__ Cb)
{
  constexpr int NXBC = NZ + 2*NDS;
  constexpr int NTOT = 2*NZ + 2*NDS + NDT;
  constexpr int NZQ  = NZ/4;
  constexpr int NDSQ = NDS/4;
  constexpr int XP   = DIN + 1;
  __shared__ float xt[66*XP];
  __shared__ __align__(16) float wl[NTOT*DIN];
  __shared__ float cwl[NXBC*3];
  __shared__ float cbl[NXBC];
  __shared__ float ibl[NTOT];
  __shared__ float dts[64*NDT];
  __shared__ float hp[NXBC*2];
  int tid = threadIdx.x;
  int seq = blockIdx.x >> 6;
  int l0  = (blockIdx.x & 63) << 6;
  for (int i = tid; i < NTOT*DIN; i += 256) wl[i] = in_w[i];
  for (int i = tid; i < NXBC*3; i += 256) cwl[i] = conv_w[i];
  for (int i = tid; i < NXBC; i += 256) cbl[i] = conv_b[i];
  for (int i = tid; i < NTOT; i += 256) ibl[i] = in_b[i];
  const float* sp; int sstr;
  if (srcMode == 0) { sp = src + (size_t)seq*LL*DIN; sstr = DIN; }
  else { sp = src + (size_t)(seq & 3)*LL*CCH + (seq >> 2)*16; sstr = CCH; }
  for (int i = tid; i < 66*DIN; i += 256) {
    int r = i / DIN, d = i % DIN;
    int l = l0 - 2 + r;
    xt[r*XP + d] = (l >= 0) ? sp[(size_t)l*sstr + d] : 0.f;
  }
  __syncthreads();
  for (int i = tid; i < 2*NXBC; i += 256) {
    int t = i & 1, ch = i >> 1;
    const float* wr = &wl[(NZ + ch)*DIN];
    const float* xp = &xt[t*XP];
    float acc = 0.f;
#pragma unroll
    for (int d = 0; d < DIN; ++d) acc += xp[d]*wr[d];
    hp[ch*2 + t] = acc;
  }
  __syncthreads();
  int l = tid & 63, w4 = tid >> 6;
  float xr2[DIN];
#pragma unroll
  for (int d = 0; d < DIN; ++d) xr2[d] = xt[(l+2)*XP + d];
  auto dotw = [&](int row) -> float {
    const float* wr = &wl[row*DIN];
    float acc = 0.f;
#pragma unroll
    for (int q4 = 0; q4 < DIN/4; ++q4) {
      float4 wv = *(const float4*)(wr + 4*q4);
      acc += xr2[4*q4]*wv.x + xr2[4*q4+1]*wv.y + xr2[4*q4+2]*wv.z + xr2[4*q4+3]*wv.w;
    }
    return acc;
  };
  size_t gl = (size_t)seq*LL + l0 + l;
  int tok = l0 + l;
  float v0ok = (tok >= 2) ? 1.f : 0.f;
  float v1ok = (tok >= 1) ? 1.f : 0.f;
  {
    float zv[NZQ];
#pragma unroll
    for (int j = 0; j < NZQ; ++j) {
      int row = w4*NZQ + j;
      zv[j] = ibl[row] + dotw(row);
    }
#pragma unroll
    for (int g = 0; g < NZQ/4; ++g)
      *(float4*)&zb[gl*NZ + w4*NZQ + 4*g] = make_float4(zv[4*g], zv[4*g+1], zv[4*g+2], zv[4*g+3]);
  }
  if (w4 < NDT) {
    int row = NTOT - NDT + w4;
    dts[l*NDT + w4] = softplusf(ibl[row] + dt_bias[w4] + dotw(row));
  }
  auto convch = [&](int ch) -> float {
    int row = NZ + ch;
    float pm = dotw(row);
    float m1 = __shfl_up(pm, 1, 64);
    float m2 = __shfl_up(pm, 2, 64);
    float h0 = hp[ch*2 + 0], h1 = hp[ch*2 + 1];
    if (l == 0) m1 = h1;
    m2 = (l == 0) ? h0 : ((l == 1) ? h1 : m2);
    float ib = ibl[row];
    float conv = cbl[ch] + (m2+ib)*v0ok*cwl[ch*3+0] + (m1+ib)*v1ok*cwl[ch*3+1] + (pm+ib)*cwl[ch*3+2];
    return siluf(conv);
  };
  {
    float xv[NZQ];
#pragma unroll
    for (int j = 0; j < NZQ; ++j) xv[j] = convch(w4*NZQ + j);
#pragma unroll
    for (int g = 0; g < NZQ/4; ++g)
      *(float4*)&xsb[gl*NZ + w4*NZQ + 4*g] = make_float4(xv[4*g], xv[4*g+1], xv[4*g+2], xv[4*g+3]);
  }
  {
    float bv[NDSQ];
#pragma unroll
    for (int j = 0; j < NDSQ; ++j) bv[j] = convch(NZ + w4*NDSQ + j);
#pragma unroll
    for (int g = 0; g < NDSQ/4; ++g)
      *(float4*)&Bb[gl*NDS + w4*NDSQ + 4*g] = make_float4(bv[4*g], bv[4*g+1], bv[4*g+2], bv[4*g+3]);
  }
  {
    float cv[NDSQ];
#pragma unroll
    for (int j = 0; j < NDSQ; ++j) cv[j] = convch(NZ + NDS + w4*NDSQ + j);
#pragma unroll
    for (int g = 0; g < NDSQ/4; ++g)
      *(float4*)&Cb[gl*NDS + w4*NDSQ + 4*g] = make_float4(cv[4*g], cv[4*g+1], cv[4*g+2], cv[4*g+3]);
  }
  __syncthreads();
  if (tid < 64) {
    if constexpr (NDT == 4) {
      *(float4*)&dtb[((size_t)seq*LL + l0 + tid)*4] =
          make_float4(dts[tid*4], dts[tid*4+1], dts[tid*4+2], dts[tid*4+3]);
    } else {
      *(float2*)&dtb[((size_t)seq*LL + l0 + tid)*NDT] = make_float2(dts[tid*NDT], dts[tid*NDT+1]);
    }
  }
}

// ======= FUSED inproj + intra-chunk SSD v7 (cascade) — best measured (R4) =======
__global__ __launch_bounds__(256, 4) void k_inssd(
    const float* __restrict__ src, int srcMode,
    const float* __restrict__ in_w, const float* __restrict__ in_b,
    const float* __restrict__ conv_w, const float* __restrict__ conv_b,
    const float* __restrict__ dt_bias, const float* __restrict__ A_log,
    const float* __restrict__ Dp,
    float* __restrict__ zb, float* __restrict__ Cb,
    float* __restrict__ ybuf, float* __restrict__ states,
    float* __restrict__ cdec, float* __restrict__ acsOut)
{
  const int DIN = 16, NZ = 32, NDS = 64, DI = 32;
  const int NXBC = 160, NTOT = 196;
  __shared__ __align__(16) float sm[10240];  // 40960 B -> 4 blocks/CU
  float* Bt  = sm;            // [0,4096)     phase-1 write, phase-2 read
  float* Ct  = sm + 4096;     // [4096,8192)  phase 2
  float* xde = sm + 8192;     // [8192,10240) phase 2
  float* hp  = sm + 4096;     // [4096,4416)  phase-1 only (aliases Ct)
  float* ha  = sm + 4416;     // [4416,4448)  phase-1 only
  int tid = threadIdx.x;
  int cid = blockIdx.x & 63;
  int seq = blockIdx.x >> 6;
  int l0  = cid << 6;
  int lane = tid & 63;
  int w = __builtin_amdgcn_readfirstlane(tid >> 6);  // wave-uniform head index
  const float* sp; int sstr;
  if (srcMode == 0) { sp = src + (size_t)seq*LL*DIN; sstr = DIN; }
  else { sp = src + (size_t)(seq & 3)*LL*CCH + (seq >> 2)*16; sstr = CCH; }
  float xr2[DIN];
  {
    const float* p = sp + (size_t)(l0 + lane)*sstr;
#pragma unroll
    for (int k = 0; k < 4; ++k) {
      float4 v = *(const float4*)(p + 4*k);
      xr2[4*k+0]=v.x; xr2[4*k+1]=v.y; xr2[4*k+2]=v.z; xr2[4*k+3]=v.w;
    }
  }
  if (tid < 32) {
    int t = tid >> 4, d = tid & 15;
    int tok = l0 - 2 + t;
    ha[t*16 + d] = (tok >= 0) ? sp[(size_t)tok*sstr + d] : 0.f;
  }
  __syncthreads();
  // halo pre-products
  for (int i = tid; i < 2*NXBC; i += 256) {
    int t = i & 1, ch = i >> 1;
    const float* wr = in_w + (size_t)(NZ + ch)*DIN;
    const float* hr = &ha[t*16];
    float4 w0 = *(const float4*)(wr),    w1 = *(const float4*)(wr+4);
    float4 w2 = *(const float4*)(wr+8),  w3 = *(const float4*)(wr+12);
    float4 h0 = *(const float4*)(hr),    h1 = *(const float4*)(hr+4);
    float4 h2 = *(const float4*)(hr+8),  h3 = *(const float4*)(hr+12);
    float acc = h0.x*w0.x + h0.y*w0.y + h0.z*w0.z + h0.w*w0.w
              + h1.x*w1.x + h1.y*w1.y + h1.z*w1.z + h1.w*w1.w
              + h2.x*w2.x + h2.y*w2.y + h2.z*w2.z + h2.w*w2.w
              + h3.x*w3.x + h3.y*w3.y + h3.z*w3.z + h3.w*w3.w;
    hp[ch*2 + t] = acc;
  }
  __syncthreads();
  // scalar-pipe weight dot (wave-uniform row -> s_load)
  auto dot16 = [&](int row) -> float {
    const float* wr = in_w + (size_t)row*DIN;
    float4 w0 = *(const float4*)(wr),    w1 = *(const float4*)(wr+4);
    float4 w2 = *(const float4*)(wr+8),  w3 = *(const float4*)(wr+12);
    return xr2[0]*w0.x  + xr2[1]*w0.y  + xr2[2]*w0.z  + xr2[3]*w0.w
         + xr2[4]*w1.x  + xr2[5]*w1.y  + xr2[6]*w1.z  + xr2[7]*w1.w
         + xr2[8]*w2.x  + xr2[9]*w2.y  + xr2[10]*w2.z + xr2[11]*w2.w
         + xr2[12]*w3.x + xr2[13]*w3.y + xr2[14]*w3.z + xr2[15]*w3.w;
  };
  size_t gl = (size_t)seq*LL + l0 + lane;
  int tok = l0 + lane;
  float v0ok = (tok >= 2) ? 1.f : 0.f;
  float v1ok = (tok >= 1) ? 1.f : 0.f;
  {
    float zv[8];
#pragma unroll
    for (int j = 0; j < 8; ++j) {
      int row = w*8 + j;
      zv[j] = in_b[row] + dot16(row);
    }
    *(float4*)&zb[gl*NZ + w*8 + 0] = make_float4(zv[0], zv[1], zv[2], zv[3]);
    *(float4*)&zb[gl*NZ + w*8 + 4] = make_float4(zv[4], zv[5], zv[6], zv[7]);
  }
  float dtv;
  {
    int row = NTOT - 4 + w;
    dtv = softplusf(in_b[row] + dt_bias[w] + dot16(row));
  }
  auto convch = [&](int ch) -> float {
    int row = NZ + ch;
    float pm = dot16(row);
    float m1 = __shfl_up(pm, 1, 64);
    float m2 = __shfl_up(pm, 2, 64);
    float2 h01 = *(const float2*)&hp[ch*2];
    if (lane == 0) m1 = h01.y;
    m2 = (lane == 0) ? h01.x : ((lane == 1) ? h01.y : m2);
    float ib = in_b[row];
    float conv = conv_b[ch] + (m2+ib)*v0ok*conv_w[ch*3+0] + (m1+ib)*v1ok*conv_w[ch*3+1]
               + (pm+ib)*conv_w[ch*3+2];
    return siluf(conv);
  };
  // xs head w: registers only
  float xv[8];
#pragma unroll
  for (int j = 0; j < 8; ++j) xv[j] = convch(w*8 + j);
  // B conv channels -> Bt (disjoint from phase-1 aliases)
#pragma unroll
  for (int j = 0; j < 16; ++j) {
    int n = w*16 + j;
    Bt[swz(n, lane)] = convch(NZ + n);
  }
  // C conv channels: regs across the phase barrier (Ct aliases hp/ha)
  float cv[16];
#pragma unroll
  for (int j = 0; j < 16; ++j) cv[j] = convch(NZ + NDS + w*16 + j);
#pragma unroll
  for (int g = 0; g < 4; ++g)
    *(float4*)&Cb[gl*NDS + w*16 + 4*g] = make_float4(cv[4*g], cv[4*g+1], cv[4*g+2], cv[4*g+3]);
  // A-cumsum (register/shuffle only)
  float Aval = -__expf(A_log[w]);
  float Dh = Dp[w];
  float v = dtv * Aval;
#pragma unroll
  for (int off = 1; off < 64; off <<= 1) {
    float t = __shfl_up(v, off, 64);
    if (lane >= off) v += t;
  }
  float acs_l = v;
  float m = __shfl(v, 31, 64);
  float acsLast = __shfl(v, 63, 64);
  float el = __expf(fminf(acs_l - m, 60.f));
  float fl = __expf(fminf(m - acs_l, 60.f));
  __syncthreads();   // === phase barrier: hp/ha reads done ===
#pragma unroll
  for (int j = 0; j < 16; ++j) Ct[swz(w*16 + j, lane)] = cv[j];
  {
    float s1 = dtv*fl;
    float* xe = &xde[(w*64 + lane)*8];
    *(float4*)xe     = make_float4(xv[0]*s1, xv[1]*s1, xv[2]*s1, xv[3]*s1);
    *(float4*)(xe+4) = make_float4(xv[4]*s1, xv[5]*s1, xv[6]*s1, xv[7]*s1);
  }
  __syncthreads();
  int lt = (tid >> 4) << 2, st = (tid & 15) << 2;
  float acc[4][4] = {};
#pragma unroll 4
  for (int n = 0; n < 64; ++n) {
    float4 cvv = *(const float4*)&Ct[swz(n, lt)];
    float4 bvv = *(const float4*)&Bt[swz(n, st)];
    float cc[4] = {cvv.x, cvv.y, cvv.z, cvv.w};
    float bb[4] = {bvv.x, bvv.y, bvv.z, bvv.w};
#pragma unroll
    for (int i2 = 0; i2 < 4; ++i2)
#pragma unroll
      for (int j2 = 0; j2 < 4; ++j2)
        acc[i2][j2] += cc[i2]*bb[j2];
  }
  __syncthreads();
#pragma unroll
  for (int j = 0; j < 4; ++j) {
    *(float4*)&Ct[swz(st + j, lt)] = make_float4(acc[0][j], acc[1][j], acc[2][j], acc[3][j]);
  }
  __syncthreads();
  // ---- merged Yd + states: xde rows via broadcast b128; B via float4/4-tokens ----
  int lg = lane >> 2, lm = lane & 3;
  float ya[8] = {0,0,0,0,0,0,0,0};
  float sa[8] = {0,0,0,0,0,0,0,0};
#pragma unroll 2
  for (int s4 = 0; s4 < 64; s4 += 4) {
    float4 b4 = *(const float4*)&Bt[swz(lane, s4)];   // tokens s4..s4+3, channel=lane
    float bb[4] = {b4.x, b4.y, b4.z, b4.w};
#pragma unroll
    for (int u = 0; u < 4; ++u) {
      int s = s4 + u;
      float g = Ct[(s << 6) + (((lg ^ ((s >> 2) & 15))) << 2 | lm)];
      g = (s <= lane) ? g : 0.f;
      float b = bb[u];
      const float* xr = &xde[(w*64 + s)*8];
      float4 a0 = *(const float4*)xr, a1 = *(const float4*)(xr + 4);
      ya[0] += g*a0.x; ya[1] += g*a0.y; ya[2] += g*a0.z; ya[3] += g*a0.w;
      ya[4] += g*a1.x; ya[5] += g*a1.y; ya[6] += g*a1.z; ya[7] += g*a1.w;
      sa[0] += b*a0.x; sa[1] += b*a0.y; sa[2] += b*a0.z; sa[3] += b*a0.w;
      sa[4] += b*a1.x; sa[5] += b*a1.y; sa[6] += b*a1.z; sa[7] += b*a1.w;
    }
  }
  float* yp = &ybuf[gl*DI + w*8];
  *(float4*)yp     = make_float4(ya[0]*el + Dh*xv[0], ya[1]*el + Dh*xv[1],
                                 ya[2]*el + Dh*xv[2], ya[3]*el + Dh*xv[3]);
  *(float4*)(yp+4) = make_float4(ya[4]*el + Dh*xv[4], ya[5]*el + Dh*xv[5],
                                 ya[6]*el + Dh*xv[6], ya[7]*el + Dh*xv[7]);
  {
    float r2 = __expf(acsLast - m);
    float* sp2 = &states[(((size_t)seq*4 + w)*NCHK + cid)*(size_t)(8*NDS) + lane*8];
    *(float4*)sp2     = make_float4(sa[0]*r2, sa[1]*r2, sa[2]*r2, sa[3]*r2);
    *(float4*)(sp2+4) = make_float4(sa[4]*r2, sa[5]*r2, sa[6]*r2, sa[7]*r2);
  }
  if (lane == 63) cdec[((size_t)seq*4 + w)*NCHK + cid] = __expf(acsLast);
  acsOut[((size_t)seq*4 + w)*LL + l0 + lane] = acs_l;
}

// ---------------- SSD intra-chunk v4 (seed path) ----------------
template<int DS, int NH>
__global__ __launch_bounds__(256) void k_ssd1(
    const float* __restrict__ xs, const float* __restrict__ dtb,
    const float* __restrict__ Bb, const float* __restrict__ Cb,
    const float* __restrict__ A_log, const float* __restrict__ Dp,
    float* __restrict__ ybuf, float* __restrict__ states,
    float* __restrict__ cdec, float* __restrict__ acsOut)
{
  constexpr int DI = NH*8;
  constexpr int NG = DS/4;
  __shared__ __align__(16) float BtBl[DS*64];
  __shared__ __align__(16) float CtGt[64*64];
  __shared__ __align__(16) float xde[NH*64*8];
  int tid = threadIdx.x;
  int cid = blockIdx.x & 63;
  int seq = blockIdx.x >> 6;
  int l0  = cid << 6;
  for (int i = tid; i < 16*DS; i += 256) {
    int ng = i % NG, l = i / NG;
    size_t g = ((size_t)seq*LL + l0 + l)*DS + 4*ng;
    float4 bv = *(const float4*)&Bb[g];
    float4 cv = *(const float4*)&Cb[g];
    BtBl[swz(4*ng+0, l)] = bv.x; BtBl[swz(4*ng+1, l)] = bv.y;
    BtBl[swz(4*ng+2, l)] = bv.z; BtBl[swz(4*ng+3, l)] = bv.w;
    CtGt[swz(4*ng+0, l)] = cv.x; CtGt[swz(4*ng+1, l)] = cv.y;
    CtGt[swz(4*ng+2, l)] = cv.z; CtGt[swz(4*ng+3, l)] = cv.w;
  }
  __syncthreads();
  int lt = (tid >> 4) << 2, st = (tid & 15) << 2;
  float acc[4][4] = {};
#pragma unroll 4
  for (int n = 0; n < DS; ++n) {
    float4 cv = *(const float4*)&CtGt[swz(n, lt)];
    float4 bv = *(const float4*)&BtBl[swz(n, st)];
    float cc[4] = {cv.x, cv.y, cv.z, cv.w};
    float bb[4] = {bv.x, bv.y, bv.z, bv.w};
#pragma unroll
    for (int i2 = 0; i2 < 4; ++i2)
#pragma unroll
      for (int j2 = 0; j2 < 4; ++j2)
        acc[i2][j2] += cc[i2]*bb[j2];
  }
  __syncthreads();
#pragma unroll
  for (int j = 0; j < 4; ++j) {
    float4 gv = make_float4(acc[0][j], acc[1][j], acc[2][j], acc[3][j]);
    *(float4*)&CtGt[swz(st + j, lt)] = gv;
  }
  for (int i = tid; i < 16*DS; i += 256) {
    int ng = i % NG, l = i / NG;
    float4 bv = *(const float4*)&Bb[((size_t)seq*LL + l0 + l)*DS + 4*ng];
    *(float4*)&BtBl[l*DS + 4*ng] = bv;
  }
  __syncthreads();
  int w = tid >> 6, lane = tid & 63;
  if (w < NH) {
    int h = w;
    float dt_l = dtb[((size_t)seq*LL + l0 + lane)*NH + h];
    float Aval = -__expf(A_log[h]);
    float Dh = Dp[h];
    float v = dt_l * Aval;
#pragma unroll
    for (int off = 1; off < 64; off <<= 1) {
      float t = __shfl_up(v, off, 64);
      if (lane >= off) v += t;
    }
    float acs_l = v;
    float m = __shfl(v, 31, 64);
    float acsLast = __shfl(v, 63, 64);
    float el = __expf(fminf(acs_l - m, 60.f));
    float fl = __expf(fminf(m - acs_l, 60.f));
    const float* xp = &xs[((size_t)seq*LL + l0 + lane)*DI + h*8];
    float4 x0 = *(const float4*)xp, x1 = *(const float4*)(xp + 4);
    float s1 = dt_l*fl;
    float* xe = &xde[(h*64 + lane)*8];
    *(float4*)xe     = make_float4(x0.x*s1, x0.y*s1, x0.z*s1, x0.w*s1);
    *(float4*)(xe+4) = make_float4(x1.x*s1, x1.y*s1, x1.z*s1, x1.w*s1);
    int lg = lane >> 2, lm = lane & 3;
    float ya[8] = {0,0,0,0,0,0,0,0};
#pragma unroll 4
    for (int s = 0; s < 64; ++s) {
      float g = CtGt[(s << 6) + ((((lg ^ ((s >> 2) & 15))) << 2) | lm)];
      g = (s <= lane) ? g : 0.f;
      const float* xr = &xde[(h*64 + s)*8];
      float4 a0 = *(const float4*)xr, a1 = *(const float4*)(xr + 4);
      ya[0] += g*a0.x; ya[1] += g*a0.y; ya[2] += g*a0.z; ya[3] += g*a0.w;
      ya[4] += g*a1.x; ya[5] += g*a1.y; ya[6] += g*a1.z; ya[7] += g*a1.w;
    }
    float* yp = &ybuf[((size_t)seq*LL + l0 + lane)*DI + h*8];
    *(float4*)yp     = make_float4(ya[0]*el + Dh*x0.x, ya[1]*el + Dh*x0.y,
                                   ya[2]*el + Dh*x0.z, ya[3]*el + Dh*x0.w);
    *(float4*)(yp+4) = make_float4(ya[4]*el + Dh*x1.x, ya[5]*el + Dh*x1.y,
                                   ya[6]*el + Dh*x1.z, ya[7]*el + Dh*x1.w);
    if (lane < DS) {
      float r2 = __expf(acsLast - m);
      float sa[8] = {0,0,0,0,0,0,0,0};
#pragma unroll 4
      for (int ll = 0; ll < 64; ++ll) {
        float b = BtBl[ll*DS + lane];
        const float* xr = &xde[(h*64 + ll)*8];
        float4 a0 = *(const float4*)xr, a1 = *(const float4*)(xr + 4);
        sa[0] += b*a0.x; sa[1] += b*a0.y; sa[2] += b*a0.z; sa[3] += b*a0.w;
        sa[4] += b*a1.x; sa[5] += b*a1.y; sa[6] += b*a1.z; sa[7] += b*a1.w;
      }
      float* sp2 = &states[(((size_t)seq*NH + h)*NCHK + cid)*(size_t)(8*DS) + lane*8];
      *(float4*)sp2     = make_float4(sa[0]*r2, sa[1]*r2, sa[2]*r2, sa[3]*r2);
      *(float4*)(sp2+4) = make_float4(sa[4]*r2, sa[5]*r2, sa[6]*r2, sa[7]*r2);
    }
    if (lane == 63) cdec[((size_t)seq*NH + h)*NCHK + cid] = __expf(acsLast);
    acsOut[((size_t)seq*NH + h)*LL + l0 + lane] = acs_l;
  }
}

// ---------------- inter-chunk scan ----------------
__global__ __launch_bounds__(512) void k_scan(float* __restrict__ st, const float* __restrict__ cd,
                                              int PN)
{
  int tid = threadIdx.x;
  size_t base = (size_t)blockIdx.x * NCHK * PN + tid;
  const float* c = cd + (size_t)blockIdx.x * NCHK;
  float carry = 0.f;
  for (int k = 0; k < NCHK; ++k) {
    size_t a = base + (size_t)k*PN;
    float s = st[a];
    st[a] = carry;
    carry = carry*c[k] + s;
  }
}

// ======= FUSED Yo + gating + RMSNorm + out-proj v5 =======
// v5: phase-1 retiled 4-tokens x 2-j per lane (1.5x less LDS read volume:
//     Ct2 as b128 over 4 swizzled-contiguous tokens, pvs as float2);
//     gm fan-in via contention-free per-block scatter (atomics removed - R5/R6
//     regression); prefetch dropped (measured neutral, R6).
template<int DS, int NH, int DOUT>
__global__ __launch_bounds__(256, 4) void k_yogate(
    const float* __restrict__ ybuf, const float* __restrict__ Cb,
    const float* __restrict__ prevSt, const float* __restrict__ acsG,
    const float* __restrict__ zb,
    const float* __restrict__ rms_w, const float* __restrict__ out_w,
    float* __restrict__ dst, int resMode, const float* __restrict__ res,
    const float* __restrict__ skipPtr, float* __restrict__ gmP)
{
  constexpr int DI = NH*8;
  constexpr int NG = DS/4;
  constexpr int DIP = DI + 4;
  constexpr int OQ = DOUT/4;
  __shared__ __align__(16) float Ct2[DS*64];
  __shared__ __align__(16) float pvs[NH*DS*8];
  __shared__ __align__(16) float gt[64*DIP];
  __shared__ float ps[NH*64];
  __shared__ __align__(16) float ow[DOUT*DI];
  __shared__ float rwl[DI];
  int tid = threadIdx.x;
  int cid = blockIdx.x & 63;
  int seq = blockIdx.x >> 6;
  int l0  = cid << 6;
  int lane = tid & 63, w = tid >> 6;
  // ---- LDS staging ----
  for (int i = tid; i < 16*DS; i += 256) {
    int ng = i % NG, l = i / NG;
    float4 cv = *(const float4*)&Cb[((size_t)seq*LL + l0 + l)*DS + 4*ng];
    Ct2[swz(4*ng+0, l)] = cv.x; Ct2[swz(4*ng+1, l)] = cv.y;
    Ct2[swz(4*ng+2, l)] = cv.z; Ct2[swz(4*ng+3, l)] = cv.w;
  }
  for (int i = tid; i < NH*DS*2; i += 256) {
    int h = i / (DS*2), o4 = i % (DS*2);
    float4 pv = *(const float4*)&prevSt[(((size_t)seq*NH + h)*NCHK + cid)*(size_t)(DS*8) + o4*4];
    *(float4*)&pvs[h*DS*8 + o4*4] = pv;
  }
  for (int i = tid; i < DOUT*DI/4; i += 256)
    *(float4*)&ow[i*4] = *(const float4*)&out_w[i*4];
  for (int i = tid; i < DI; i += 256) rwl[i] = rms_w[i];
  __syncthreads();
  // ---- phase 1: Yo + gating, 4-token x 2-j tile per lane ----
  if (w < NH) {
    int tg = (lane & 15) << 2;     // 4 tokens tg..tg+3
    int jp = (lane >> 4) << 1;     // j-pair jp, jp+1
    float a00=0,a01=0,a10=0,a11=0,a20=0,a21=0,a30=0,a31=0;
#pragma unroll 4
    for (int n = 0; n < DS; ++n) {
      float4 c4 = *(const float4*)&Ct2[swz(n, tg)];
      float2 p2 = *(const float2*)&pvs[(w*DS + n)*8 + jp];
      a00 += c4.x*p2.x; a01 += c4.x*p2.y;
      a10 += c4.y*p2.x; a11 += c4.y*p2.y;
      a20 += c4.z*p2.x; a21 += c4.z*p2.y;
      a30 += c4.w*p2.x; a31 += c4.w*p2.y;
    }
    float ac[4][2] = {{a00,a01},{a10,a11},{a20,a21},{a30,a31}};
    float psum[4];
#pragma unroll
    for (int t = 0; t < 4; ++t) {
      int token = tg + t;
      float el = __expf(acsG[((size_t)seq*NH + w)*LL + l0 + token]);
      size_t gi = ((size_t)seq*LL + l0 + token)*DI + w*8 + jp;
      float2 y2 = *(const float2*)&ybuf[gi];
      float2 z2 = *(const float2*)&zb[gi];
      float g0 = (y2.x + el*ac[t][0]) * siluf(z2.x);
      float g1 = (y2.y + el*ac[t][1]) * siluf(z2.y);
      *(float2*)&gt[token*DIP + w*8 + jp] = make_float2(g0, g1);
      psum[t] = g0*g0 + g1*g1;
    }
#pragma unroll
    for (int t = 0; t < 4; ++t) {
      psum[t] += __shfl_xor(psum[t], 16, 64);
      psum[t] += __shfl_xor(psum[t], 32, 64);
    }
    if (lane < 16) {
#pragma unroll
      for (int t = 0; t < 4; ++t) ps[w*64 + tg + t] = psum[t];
    }
  }
  __syncthreads();
  // ---- phase 2: RMSNorm + out-proj (token = lane, channel group = wave) ----
  int tok = lane, q = w;
  float rsum = 0.f;
#pragma unroll
  for (int h = 0; h < NH; ++h) rsum += ps[h*64 + tok];
  float r = rsqrtf(rsum*(1.f/DI) + 1e-5f);
  float gr[DI];
#pragma unroll
  for (int k = 0; k < DI/4; ++k) {
    float4 v = *(const float4*)&gt[tok*DIP + 4*k];
    gr[4*k+0] = v.x*r*rwl[4*k+0];
    gr[4*k+1] = v.y*r*rwl[4*k+1];
    gr[4*k+2] = v.z*r*rwl[4*k+2];
    gr[4*k+3] = v.w*r*rwl[4*k+3];
  }
  int l = l0 + tok;
  const float* rp = nullptr; float skip = 1.f;
  if (resMode == 1) rp = res + ((size_t)seq*LL + l)*DOUT + q*OQ;
  else if (resMode == 2) {
    int s = seq / B_, b = seq % B_;
    rp = res + ((size_t)b*LL + l)*CCH + s*DOUT + q*OQ;
    skip = skipPtr[0];
  }
  float ov[OQ];
#pragma unroll
  for (int j = 0; j < OQ; ++j) {
    int o = q*OQ + j;
    const float* wr = &ow[o*DI];
    float acc2 = 0.f;
#pragma unroll
    for (int k = 0; k < DI/4; ++k) {
      float4 wv = *(const float4*)(wr + 4*k);
      acc2 += gr[4*k]*wv.x + gr[4*k+1]*wv.y + gr[4*k+2]*wv.z + gr[4*k+3]*wv.w;
    }
    if (rp) acc2 += skip * rp[j];
    ov[j] = acc2;
  }
  float* dp = &dst[((size_t)seq*LL + l)*DOUT + q*OQ];
  if constexpr (OQ == 4) *(float4*)dp = make_float4(ov[0], ov[1], ov[2], ov[3]);
  else *(float2*)dp = make_float2(ov[0], ov[1]);
  // gm partial sums: per-wave token reduce, contention-free per-block scatter
  if (gmP) {
#pragma unroll
    for (int j = 0; j < OQ; ++j) {
      float sv = ov[j];
#pragma unroll
      for (int off = 32; off > 0; off >>= 1) sv += __shfl_down(sv, off, 64);
      if (tok == 0) gmP[(((size_t)seq*NCHK + cid))*DOUT + q*OQ + j] = sv;
    }
  }
}

// ---------------- LN over C of x[b,c,l] -> xn[b,l,c] ----------------
__global__ __launch_bounds__(256) void k_ln1(const float* __restrict__ x,
    const float* __restrict__ w, const float* __restrict__ bb, float* __restrict__ xn)
{
  __shared__ float tile[128*65];
  __shared__ float mu[64], rs[64];
  int tid = threadIdx.x;
  int b = blockIdx.x >> 6;
  int l0 = (blockIdx.x & 63) << 6;
  for (int i = tid; i < 8192; i += 256) {
    int l = i & 63, c = i >> 6;
    tile[c*65 + l] = x[((size_t)b*CCH + c)*LL + l0 + l];
  }
  __syncthreads();
  if (tid < 64) {
    float s = 0.f;
    for (int c = 0; c < CCH; ++c) s += tile[c*65 + tid];
    float m = s * (1.f/CCH);
    float v = 0.f;
    for (int c = 0; c < CCH; ++c) { float d = tile[c*65 + tid] - m; v += d*d; }
    mu[tid] = m; rs[tid] = rsqrtf(v*(1.f/CCH) + 1e-5f);
  }
  __syncthreads();
  for (int i = tid; i < 8192; i += 256) {
    int c = i & 127, l = i >> 7;
    xn[((size_t)b*LL + l0 + l)*CCH + c] = (tile[c*65 + l] - mu[l])*rs[l]*w[c] + bb[c];
  }
}

// ---------------- gmix: reduce gmP over chunks, softmax-mix, scale 1/LL ----------------
__global__ __launch_bounds__(256) void k_mix(const float* __restrict__ gmP,
    const float* __restrict__ crossW, float* __restrict__ gmix)
{
  __shared__ float wsm[64];
  __shared__ float gs[512];
  int tid = threadIdx.x;
  // phase A: reduce over the 64 chunks
  for (int i = tid; i < 512; i += 256) {
    int sq = i >> 4, c = i & 15;
    const float* p = gmP + ((size_t)sq*NCHK)*16 + c;
    float acc = 0.f;
    for (int cid = 0; cid < NCHK; ++cid) acc += p[cid*16];
    gs[i] = acc;
  }
  if (tid < 8) {
    float mx = -1e30f;
    for (int p = 0; p < 8; ++p) mx = fmaxf(mx, crossW[tid*8 + p]);
    float e[8]; float s = 0.f;
    for (int p = 0; p < 8; ++p) { e[p] = __expf(crossW[tid*8 + p] - mx); s += e[p]; }
    for (int p = 0; p < 8; ++p) wsm[tid*8 + p] = e[p] / s;
  }
  __syncthreads();
  for (int i = tid; i < 512; i += 256) {
    int c = i & 15; int bb = (i >> 4) & 3; int p = i >> 6;
    float acc = 0.f;
    for (int q = 0; q < 8; ++q)
      acc += gs[(q*B_ + bb)*16 + c] * (1.f/LL) * wsm[q*8 + p];
    gmix[((size_t)(p*B_ + bb))*16 + c] = acc;
  }
}

// ---------------- assemble ys+gmix, LN2, + (x + detok(gf2)) -> outb[b,c,l] ----------------
__global__ __launch_bounds__(256) void k_out2(const float* __restrict__ ys,
    const float* __restrict__ gmix, const float* __restrict__ w, const float* __restrict__ bb,
    const float* __restrict__ x, const float* __restrict__ gf2,
    const float* __restrict__ dw, const float* __restrict__ db,
    float* __restrict__ outb)
{
  __shared__ float tile[128*65];
  __shared__ float mu[64], rs[64];
  int tid = threadIdx.x;
  int b = blockIdx.x >> 6;
  int l0 = (blockIdx.x & 63) << 6;
  for (int i = tid; i < 8192; i += 256) {
    int c = i & 15; int l = (i >> 4) & 63; int s = i >> 10;
    int seq = s*B_ + b;
    tile[(s*16 + c)*65 + l] = ys[((size_t)seq*LL + l0 + l)*16 + c] + gmix[(size_t)seq*16 + c];
  }
  __syncthreads();
  if (tid < 64) {
    float sm = 0.f;
    for (int c = 0; c < 128; ++c) sm += tile[c*65 + tid];
    float m = sm * (1.f/128.f);
    float v = 0.f;
    for (int c = 0; c < 128; ++c) { float d = tile[c*65 + tid] - m; v += d*d; }
    mu[tid] = m; rs[tid] = rsqrtf(v*(1.f/128.f) + 1e-5f);
  }
  __syncthreads();
  int lfix = tid & 63;
  float g8[8];
  {
    const float* gp = gf2 + ((size_t)b*LL + l0 + lfix)*8;
#pragma unroll
    for (int k = 0; k < 8; ++k) g8[k] = gp[k];
  }
  for (int i = tid; i < 8192; i += 256) {
    int l = i & 63, c = i >> 6;
    size_t gi = ((size_t)b*CCH + c)*LL + l0 + l;
    float det = db[c];
#pragma unroll
    for (int k = 0; k < 8; ++k) det += g8[k]*dw[c*8 + k];
    outb[gi] = (tile[c*65 + l] - mu[l])*rs[l]*w[c] + bb[c] + x[gi] + det;
  }
}

// ---------------- fc1: register-tiled GEMM, transposed weight tile ----------------
__global__ __launch_bounds__(256) void k_fc1(const float* __restrict__ src,
    const float* __restrict__ w, const float* __restrict__ bias, float* __restrict__ dst)
{
  constexpr int WTP = 68;
  __shared__ float st[128*64];
  __shared__ __align__(16) float wtT[128*WTP];
  int tid = threadIdx.x;
  int blk = blockIdx.x;
  int ot = blk & 3;
  int lt = (blk >> 2) & 63;
  int b  = blk >> 8;
  int l0 = lt << 6, o0 = ot << 6;
  for (int i = tid; i < 8192; i += 256) {
    int l = i & 63, c = i >> 6;
    st[c*64 + l] = src[((size_t)b*CCH + c)*LL + l0 + l];
  }
  for (int i = tid; i < 8192; i += 256) {
    int c = i & 127, o = i >> 7;
    wtT[c*WTP + o] = w[(size_t)(o0 + o)*128 + c];
  }
  __syncthreads();
  int l4 = (tid & 15) << 2, o4 = (tid >> 4) << 2;
  float a0[4] = {}, a1[4] = {}, a2[4] = {}, a3[4] = {};
#pragma unroll 4
  for (int c = 0; c < 128; ++c) {
    float4 sv = *(float4*)&st[c*64 + l4];
    float4 wv = *(float4*)&wtT[c*WTP + o4];
    a0[0] += wv.x*sv.x; a0[1] += wv.x*sv.y; a0[2] += wv.x*sv.z; a0[3] += wv.x*sv.w;
    a1[0] += wv.y*sv.x; a1[1] += wv.y*sv.y; a1[2] += wv.y*sv.z; a1[3] += wv.y*sv.w;
    a2[0] += wv.z*sv.x; a2[1] += wv.z*sv.y; a2[2] += wv.z*sv.z; a2[3] += wv.z*sv.w;
    a3[0] += wv.w*sv.x; a3[1] += wv.w*sv.y; a3[2] += wv.w*sv.z; a3[3] += wv.w*sv.w;
  }
  float* rows[4] = {a0, a1, a2, a3};
#pragma unroll
  for (int j = 0; j < 4; ++j) {
    int o = o0 + o4 + j;
    float bi = bias[o];
    float* a = rows[j];
    *(float4*)&dst[((size_t)b*256 + o)*LL + l0 + l4] =
        make_float4(a[0]+bi, a[1]+bi, a[2]+bi, a[3]+bi);
  }
}

// ---------------- depthwise 3x3 + gelu, LDS-tiled ----------------
__global__ __launch_bounds__(256) void k_dw(const float* __restrict__ h1,
    const float* __restrict__ w, const float* __restrict__ bias, float* __restrict__ h2)
{
  __shared__ float tile[66*66];
  int tid = threadIdx.x;
  int blk = blockIdx.x;
  const float* base = h1 + (size_t)blk*LL;
  const float* wp = w + (blk & 255)*9;
  float bi = bias[blk & 255];
  for (int i = tid; i < 66*66; i += 256) {
    int r = i / 66, cc = i % 66;
    int gr = r - 1, gc = cc - 1;
    tile[i] = (gr >= 0 && gr < HH && gc >= 0 && gc < WW) ? base[gr*WW + gc] : 0.f;
  }
  float w00 = wp[0], w01 = wp[1], w02 = wp[2];
  float w10 = wp[3], w11 = wp[4], w12 = wp[5];
  float w20 = wp[6], w21 = wp[7], w22 = wp[8];
  __syncthreads();
  float* outp = h2 + (size_t)blk*LL;
#pragma unroll
  for (int k = 0; k < 16; ++k) {
    int j = tid + k*256;
    int row = j >> 6, col = j & 63;
    const float* t0 = &tile[row*66 + col];
    float acc = t0[0]*w00  + t0[1]*w01  + t0[2]*w02
              + t0[66]*w10 + t0[67]*w11 + t0[68]*w12
              + t0[132]*w20 + t0[133]*w21 + t0[134]*w22;
    float v = acc + bi;
    float u = 0.7978845608028654f*(v + 0.044715f*v*v*v);
    float e = __expf(2.f*u);
    float th = 1.f - 2.f/(e + 1.f);
    outp[j] = 0.5f*v*(1.f + th);
  }
}

// ---------------- fc2: register-tiled GEMM, transposed weight tile ----------------
__global__ __launch_bounds__(256) void k_fc2(const float* __restrict__ h2,
    const float* __restrict__ w, const float* __restrict__ bias,
    const float* __restrict__ resid, float* __restrict__ dst)
{
  constexpr int WTP = 36;
  __shared__ float st[128*64];
  __shared__ __align__(16) float wtT[256*WTP];
  int tid = threadIdx.x;
  int blk = blockIdx.x;
  int ct = blk & 3;
  int lt = (blk >> 2) & 63;
  int b  = blk >> 8;
  int l0 = lt << 6, c0 = ct << 5;
  for (int i = tid; i < 32*256; i += 256) {
    int o = i & 255, c = i >> 8;
    wtT[o*WTP + c] = w[(size_t)(c0 + c)*256 + o];
  }
  int l4 = (tid & 15) << 2, c2 = (tid >> 4) << 1;
  float a0[4] = {}, a1[4] = {};
  for (int ko = 0; ko < 256; ko += 128) {
    __syncthreads();
    for (int i = tid; i < 8192; i += 256) {
      int l = i & 63, o = i >> 6;
      st[o*64 + l] = h2[((size_t)b*256 + ko + o)*LL + l0 + l];
    }
    __syncthreads();
#pragma unroll 4
    for (int o = 0; o < 128; ++o) {
      float4 sv = *(float4*)&st[o*64 + l4];
      float2 wv = *(float2*)&wtT[(ko + o)*WTP + c2];
      a0[0] += wv.x*sv.x; a0[1] += wv.x*sv.y; a0[2] += wv.x*sv.z; a0[3] += wv.x*sv.w;
      a1[0] += wv.y*sv.x; a1[1] += wv.y*sv.y; a1[2] += wv.y*sv.z; a1[3] += wv.y*sv.w;
    }
  }
  float* rows[2] = {a0, a1};
#pragma unroll
  for (int j = 0; j < 2; ++j) {
    int c = c0 + c2 + j;
    float bi = bias[c];
    size_t gi = ((size_t)b*CCH + c)*LL + l0 + l4;
    float4 rv = *(const float4*)&resid[gi];
    float* a = rows[j];
    *(float4*)&dst[gi] = make_float4(a[0]+bi+rv.x, a[1]+bi+rv.y, a[2]+bi+rv.z, a[3]+bi+rv.w);
  }
}

extern "C" void kernel_launch(void* const* d_in, const int* in_sizes, int n_in,
                              void* d_out, int out_size, void* d_ws, size_t ws_size,
                              hipStream_t stream) {
  (void)in_sizes; (void)n_in; (void)out_size; (void)ws_size;
  const float* x        = (const float*)d_in[0];
  const float* tok_w    = (const float*)d_in[1];
  const float* tok_b    = (const float*)d_in[2];
  const float* detok_w  = (const float*)d_in[3];
  const float* detok_b  = (const float*)d_in[4];
  const float* sm_in_w  = (const float*)d_in[5];
  const float* sm_in_b  = (const float*)d_in[6];
  const float* sm_conv_w= (const float*)d_in[7];
  const float* sm_conv_b= (const float*)d_in[8];
  const float* sm_A_log = (const float*)d_in[9];
  const float* sm_D     = (const float*)d_in[10];
  const float* sm_dt_b  = (const float*)d_in[11];
  const float* sm_rms_w = (const float*)d_in[12];
  const float* sm_out_w = (const float*)d_in[13];
  const float* cm_in_w  = (const float*)d_in[14];
  const float* cm_in_b  = (const float*)d_in[15];
  const float* cm_conv_w= (const float*)d_in[16];
  const float* cm_conv_b= (const float*)d_in[17];
  const float* cm_A_log = (const float*)d_in[18];
  const float* cm_D     = (const float*)d_in[19];
  const float* cm_dt_b  = (const float*)d_in[20];
  const float* cm_rms_w = (const float*)d_in[21];
  const float* cm_out_w = (const float*)d_in[22];
  const float* cross_W  = (const float*)d_in[23];
  const float* n1w      = (const float*)d_in[24];
  const float* n1b      = (const float*)d_in[25];
  const float* n2w      = (const float*)d_in[26];
  const float* n2b      = (const float*)d_in[27];
  const float* fc1w     = (const float*)d_in[28];
  const float* fc1b     = (const float*)d_in[29];
  const float* dww      = (const float*)d_in[30];
  const float* dwb      = (const float*)d_in[31];
  const float* fc2w     = (const float*)d_in[32];
  const float* fc2b     = (const float*)d_in[33];
  const float* skp      = (const float*)d_in[34];
  float* ws  = (float*)d_ws;
  float* out = (float*)d_out;

  const size_t SGF0 = 0;
  const size_t SOUTn= 131072;
  const size_t XN   = 2097152;
  const size_t YS   = 4194304;
  const size_t OUTB = 6291456;
  const size_t GMIX = 8389120;
  const size_t GMP  = 8389632;           // 32*64*16 = 32768 floats
  const size_t SCR  = GMP + 32768;
  const size_t CZ   = SCR;
  const size_t CCF  = CZ   + 4194304;
  const size_t CACS = CCF  + 8388608;
  const size_t CST  = CACS + 2097152;
  const size_t CCD  = CST  + 4194304;
  const size_t CY   = CCD  + 8192;
  const size_t XB   = CY   + 4194304;
  const size_t SZ   = SCR;
  const size_t SDT  = SZ  + 262144;
  const size_t SXS  = SDT + 32768;
  const size_t SB   = SXS + 262144;
  const size_t SC   = SB  + 262144;
  const size_t SACS = SC  + 262144;
  const size_t SST  = SACS + 32768;
  const size_t SCD  = SST + 65536;
  const size_t SY   = SCD + 512;
  const size_t H1 = SCR;
  const size_t H2 = SCR + 4194304;

  // ===== seed path =====
  k_seedtok<<<B_*64, 256, 0, stream>>>(x, tok_w, tok_b, ws + SGF0);
  k_inproj<8,16,16,2><<<B_*64, 256, 0, stream>>>(ws + SGF0, 0, sm_in_w, sm_in_b, sm_conv_w,
      sm_conv_b, sm_dt_b, ws + SZ, ws + SDT, ws + SXS, ws + SB, ws + SC);
  k_ssd1<16,2><<<B_*NCHK, 256, 0, stream>>>(ws + SXS, ws + SDT, ws + SB, ws + SC,
      sm_A_log, sm_D, ws + SY, ws + SST, ws + SCD, ws + SACS);
  k_scan<<<B_*2, 128, 0, stream>>>(ws + SST, ws + SCD, 128);
  k_yogate<16,2,8><<<B_*NCHK, 256, 0, stream>>>(ws + SY, ws + SC, ws + SST, ws + SACS,
      ws + SZ, sm_rms_w, sm_out_w, ws + SOUTn, 1, ws + SGF0, skp, nullptr);

  // ===== norm1 =====
  k_ln1<<<B_*64, 256, 0, stream>>>(x, n1w, n1b, ws + XN);

  // ===== cascade layer 0 =====
  k_inssd<<<32*NCHK, 256, 0, stream>>>(ws + XN, 1, cm_in_w, cm_in_b, cm_conv_w,
      cm_conv_b, cm_dt_b, cm_A_log, cm_D, ws + CZ, ws + CCF,
      ws + CY, ws + CST, ws + CCD, ws + CACS);
  k_scan<<<32*4, 512, 0, stream>>>(ws + CST, ws + CCD, 512);
  k_yogate<64,4,16><<<32*NCHK, 256, 0, stream>>>(ws + CY, ws + CCF, ws + CST, ws + CACS,
      ws + CZ, cm_rms_w, cm_out_w, ws + XB, 0, nullptr, skp, nullptr);

  // ===== cascade layer 1 =====
  k_inssd<<<32*NCHK, 256, 0, stream>>>(ws + XB, 0, cm_in_w + 3136, cm_in_b + 196,
      cm_conv_w + 480, cm_conv_b + 160, cm_dt_b + 4, cm_A_log + 4, cm_D + 4, ws + CZ, ws + CCF,
      ws + CY, ws + CST, ws + CCD, ws + CACS);
  k_scan<<<32*4, 512, 0, stream>>>(ws + CST, ws + CCD, 512);
  k_yogate<64,4,16><<<32*NCHK, 256, 0, stream>>>(ws + CY, ws + CCF, ws + CST, ws + CACS,
      ws + CZ, cm_rms_w + 32, cm_out_w + 512, ws + YS, 2, ws + XN, skp, ws + GMP);

  // ===== cross mix + norm2 + (fused detok seed) =====
  k_mix<<<1, 256, 0, stream>>>(ws + GMP, cross_W, ws + GMIX);
  k_out2<<<B_*64, 256, 0, stream>>>(ws + YS, ws + GMIX, n2w, n2b,
      x, ws + SOUTn, detok_w, detok_b, ws + OUTB);

  // ===== FFN =====
  k_fc1<<<B_*64*4, 256, 0, stream>>>(ws + OUTB, fc1w, fc1b, ws + H1);
  k_dw<<<B_*256, 256, 0, stream>>>(ws + H1, dww, dwb, ws + H2);
  k_fc2<<<B_*64*4, 256, 0, stream>>>(ws + H2, fc2w, fc2b, ws + OUTB, out);
}

// Round 8
// 426.563 us; speedup vs baseline: 1.1826x; 1.0720x over previous
//
#include <hip/hip_runtime.h>
#include <math.h>

#define B_ 4
#define CCH 128
#define HH 64
#define WW 64
#define LL 4096
#define NCHK 64

__device__ __forceinline__ float siluf(float x) { return x / (1.f + __expf(-x)); }
__device__ __forceinline__ float softplusf(float x) { return (x > 20.f) ? x : log1pf(__expf(x)); }
// swizzled [n][l] layout, pitch 64: phys = n*64 + (((l>>2) ^ ((n>>2)&15))<<2 | (l&3))
__device__ __forceinline__ int swz(int n, int l) {
  return (n << 6) + ((((l >> 2) ^ ((n >> 2) & 15)) << 2) | (l & 3));
}

// register-pipelined inter-chunk scan body: batches of 16 independent loads,
// then the serial carry recurrence runs out of registers (breaks the
// 64 x ~400cy load->store->FMA latency chain).
__device__ __forceinline__ void scan_body(float* st, const float* cd, int PN,
                                          int scanBlk, int tid) {
  size_t base = (size_t)scanBlk * NCHK * PN + tid;
  const float* c = cd + (size_t)scanBlk * NCHK;
  float carry = 0.f;
#pragma unroll
  for (int k0 = 0; k0 < NCHK; k0 += 16) {
    float v[16];
#pragma unroll
    for (int j = 0; j < 16; ++j) v[j] = st[base + (size_t)(k0 + j)*PN];
#pragma unroll
    for (int j = 0; j < 16; ++j) {
      st[base + (size_t)(k0 + j)*PN] = carry;
      carry = carry*c[k0 + j] + v[j];
    }
  }
}

// ---------------- seed tokenize v2 ----------------
__global__ __launch_bounds__(256) void k_seedtok(const float* __restrict__ x,
    const float* __restrict__ w, const float* __restrict__ bias, float* __restrict__ gf)
{
  __shared__ float tile[128*65];
  __shared__ float sw[8*128];
  __shared__ float bl[8];
  int tid = threadIdx.x;
  int b = blockIdx.x >> 6;
  int l0 = (blockIdx.x & 63) << 6;
  for (int i = tid; i < 1024; i += 256) sw[i] = w[i];
  if (tid < 8) bl[tid] = bias[tid];
  for (int i = tid; i < 8192; i += 256) {
    int l = i & 63, c = i >> 6;
    tile[c*65 + l] = x[((size_t)b*CCH + c)*LL + l0 + l];
  }
  __syncthreads();
  int l = tid & 63, q = tid >> 6;
  float a0 = bl[2*q], a1 = bl[2*q+1];
  const float* w0 = &sw[(2*q)*128];
  const float* w1 = &sw[(2*q+1)*128];
#pragma unroll 4
  for (int c = 0; c < 128; ++c) {
    float xv = tile[c*65 + l];
    a0 += xv * w0[c];
    a1 += xv * w1[c];
  }
  *(float2*)&gf[((size_t)b*LL + l0 + l)*8 + 2*q] = make_float2(a0, a1);
}

// ---------------- fused in-projection + conv3 + silu + softplus(dt) (seed path) ----------------
template<int DIN, int NZ, int NDS, int NDT>
__global__ __launch_bounds__(256) void k_inproj(
    const float* __restrict__ src, int srcMode,
    const float* __restrict__ in_w, const float* __restrict__ in_b,
    const float* __restrict__ conv_w, const float* __restrict__ conv_b,
    const float* __restrict__ dt_bias,
    float* __restrict__ zb, float* __restrict__ dtb,
    float* __restrict__ xsb, float* __restrict__ Bb, float* __restrict__ Cb)
{
  constexpr int NXBC = NZ + 2*NDS;
  constexpr int NTOT = 2*NZ + 2*NDS + NDT;
  constexpr int NZQ  = NZ/4;
  constexpr int NDSQ = NDS/4;
  constexpr int XP   = DIN + 1;
  __shared__ float xt[66*XP];
  __shared__ __align__(16) float wl[NTOT*DIN];
  __shared__ float cwl[NXBC*3];
  __shared__ float cbl[NXBC];
  __shared__ float ibl[NTOT];
  __shared__ float dts[64*NDT];
  __shared__ float hp[NXBC*2];
  int tid = threadIdx.x;
  int seq = blockIdx.x >> 6;
  int l0  = (blockIdx.x & 63) << 6;
  for (int i = tid; i < NTOT*DIN; i += 256) wl[i] = in_w[i];
  for (int i = tid; i < NXBC*3; i += 256) cwl[i] = conv_w[i];
  for (int i = tid; i < NXBC; i += 256) cbl[i] = conv_b[i];
  for (int i = tid; i < NTOT; i += 256) ibl[i] = in_b[i];
  const float* sp; int sstr;
  if (srcMode == 0) { sp = src + (size_t)seq*LL*DIN; sstr = DIN; }
  else { sp = src + (size_t)(seq & 3)*LL*CCH + (seq >> 2)*16; sstr = CCH; }
  for (int i = tid; i < 66*DIN; i += 256) {
    int r = i / DIN, d = i % DIN;
    int l = l0 - 2 + r;
    xt[r*XP + d] = (l >= 0) ? sp[(size_t)l*sstr + d] : 0.f;
  }
  __syncthreads();
  for (int i = tid; i < 2*NXBC; i += 256) {
    int t = i & 1, ch = i >> 1;
    const float* wr = &wl[(NZ + ch)*DIN];
    const float* xp = &xt[t*XP];
    float acc = 0.f;
#pragma unroll
    for (int d = 0; d < DIN; ++d) acc += xp[d]*wr[d];
    hp[ch*2 + t] = acc;
  }
  __syncthreads();
  int l = tid & 63, w4 = tid >> 6;
  float xr2[DIN];
#pragma unroll
  for (int d = 0; d < DIN; ++d) xr2[d] = xt[(l+2)*XP + d];
  auto dotw = [&](int row) -> float {
    const float* wr = &wl[row*DIN];
    float acc = 0.f;
#pragma unroll
    for (int q4 = 0; q4 < DIN/4; ++q4) {
      float4 wv = *(const float4*)(wr + 4*q4);
      acc += xr2[4*q4]*wv.x + xr2[4*q4+1]*wv.y + xr2[4*q4+2]*wv.z + xr2[4*q4+3]*wv.w;
    }
    return acc;
  };
  size_t gl = (size_t)seq*LL + l0 + l;
  int tok = l0 + l;
  float v0ok = (tok >= 2) ? 1.f : 0.f;
  float v1ok = (tok >= 1) ? 1.f : 0.f;
  {
    float zv[NZQ];
#pragma unroll
    for (int j = 0; j < NZQ; ++j) {
      int row = w4*NZQ + j;
      zv[j] = ibl[row] + dotw(row);
    }
#pragma unroll
    for (int g = 0; g < NZQ/4; ++g)
      *(float4*)&zb[gl*NZ + w4*NZQ + 4*g] = make_float4(zv[4*g], zv[4*g+1], zv[4*g+2], zv[4*g+3]);
  }
  if (w4 < NDT) {
    int row = NTOT - NDT + w4;
    dts[l*NDT + w4] = softplusf(ibl[row] + dt_bias[w4] + dotw(row));
  }
  auto convch = [&](int ch) -> float {
    int row = NZ + ch;
    float pm = dotw(row);
    float m1 = __shfl_up(pm, 1, 64);
    float m2 = __shfl_up(pm, 2, 64);
    float h0 = hp[ch*2 + 0], h1 = hp[ch*2 + 1];
    if (l == 0) m1 = h1;
    m2 = (l == 0) ? h0 : ((l == 1) ? h1 : m2);
    float ib = ibl[row];
    float conv = cbl[ch] + (m2+ib)*v0ok*cwl[ch*3+0] + (m1+ib)*v1ok*cwl[ch*3+1] + (pm+ib)*cwl[ch*3+2];
    return siluf(conv);
  };
  {
    float xv[NZQ];
#pragma unroll
    for (int j = 0; j < NZQ; ++j) xv[j] = convch(w4*NZQ + j);
#pragma unroll
    for (int g = 0; g < NZQ/4; ++g)
      *(float4*)&xsb[gl*NZ + w4*NZQ + 4*g] = make_float4(xv[4*g], xv[4*g+1], xv[4*g+2], xv[4*g+3]);
  }
  {
    float bv[NDSQ];
#pragma unroll
    for (int j = 0; j < NDSQ; ++j) bv[j] = convch(NZ + w4*NDSQ + j);
#pragma unroll
    for (int g = 0; g < NDSQ/4; ++g)
      *(float4*)&Bb[gl*NDS + w4*NDSQ + 4*g] = make_float4(bv[4*g], bv[4*g+1], bv[4*g+2], bv[4*g+3]);
  }
  {
    float cv[NDSQ];
#pragma unroll
    for (int j = 0; j < NDSQ; ++j) cv[j] = convch(NZ + NDS + w4*NDSQ + j);
#pragma unroll
    for (int g = 0; g < NDSQ/4; ++g)
      *(float4*)&Cb[gl*NDS + w4*NDSQ + 4*g] = make_float4(cv[4*g], cv[4*g+1], cv[4*g+2], cv[4*g+3]);
  }
  __syncthreads();
  if (tid < 64) {
    if constexpr (NDT == 4) {
      *(float4*)&dtb[((size_t)seq*LL + l0 + tid)*4] =
          make_float4(dts[tid*4], dts[tid*4+1], dts[tid*4+2], dts[tid*4+3]);
    } else {
      *(float2*)&dtb[((size_t)seq*LL + l0 + tid)*NDT] = make_float2(dts[tid*NDT], dts[tid*NDT+1]);
    }
  }
}

// ======= FUSED inproj + intra-chunk SSD v7 (cascade) — best measured (R4) =======
__global__ __launch_bounds__(256, 4) void k_inssd(
    const float* __restrict__ src, int srcMode,
    const float* __restrict__ in_w, const float* __restrict__ in_b,
    const float* __restrict__ conv_w, const float* __restrict__ conv_b,
    const float* __restrict__ dt_bias, const float* __restrict__ A_log,
    const float* __restrict__ Dp,
    float* __restrict__ zb, float* __restrict__ Cb,
    float* __restrict__ ybuf, float* __restrict__ states,
    float* __restrict__ cdec, float* __restrict__ acsOut)
{
  const int DIN = 16, NZ = 32, NDS = 64, DI = 32;
  const int NXBC = 160, NTOT = 196;
  __shared__ __align__(16) float sm[10240];  // 40960 B -> 4 blocks/CU
  float* Bt  = sm;            // [0,4096)     phase-1 write, phase-2 read
  float* Ct  = sm + 4096;     // [4096,8192)  phase 2
  float* xde = sm + 8192;     // [8192,10240) phase 2
  float* hp  = sm + 4096;     // [4096,4416)  phase-1 only (aliases Ct)
  float* ha  = sm + 4416;     // [4416,4448)  phase-1 only
  int tid = threadIdx.x;
  int cid = blockIdx.x & 63;
  int seq = blockIdx.x >> 6;
  int l0  = cid << 6;
  int lane = tid & 63;
  int w = __builtin_amdgcn_readfirstlane(tid >> 6);  // wave-uniform head index
  const float* sp; int sstr;
  if (srcMode == 0) { sp = src + (size_t)seq*LL*DIN; sstr = DIN; }
  else { sp = src + (size_t)(seq & 3)*LL*CCH + (seq >> 2)*16; sstr = CCH; }
  float xr2[DIN];
  {
    const float* p = sp + (size_t)(l0 + lane)*sstr;
#pragma unroll
    for (int k = 0; k < 4; ++k) {
      float4 v = *(const float4*)(p + 4*k);
      xr2[4*k+0]=v.x; xr2[4*k+1]=v.y; xr2[4*k+2]=v.z; xr2[4*k+3]=v.w;
    }
  }
  if (tid < 32) {
    int t = tid >> 4, d = tid & 15;
    int tok = l0 - 2 + t;
    ha[t*16 + d] = (tok >= 0) ? sp[(size_t)tok*sstr + d] : 0.f;
  }
  __syncthreads();
  // halo pre-products
  for (int i = tid; i < 2*NXBC; i += 256) {
    int t = i & 1, ch = i >> 1;
    const float* wr = in_w + (size_t)(NZ + ch)*DIN;
    const float* hr = &ha[t*16];
    float4 w0 = *(const float4*)(wr),    w1 = *(const float4*)(wr+4);
    float4 w2 = *(const float4*)(wr+8),  w3 = *(const float4*)(wr+12);
    float4 h0 = *(const float4*)(hr),    h1 = *(const float4*)(hr+4);
    float4 h2 = *(const float4*)(hr+8),  h3 = *(const float4*)(hr+12);
    float acc = h0.x*w0.x + h0.y*w0.y + h0.z*w0.z + h0.w*w0.w
              + h1.x*w1.x + h1.y*w1.y + h1.z*w1.z + h1.w*w1.w
              + h2.x*w2.x + h2.y*w2.y + h2.z*w2.z + h2.w*w2.w
              + h3.x*w3.x + h3.y*w3.y + h3.z*w3.z + h3.w*w3.w;
    hp[ch*2 + t] = acc;
  }
  __syncthreads();
  // scalar-pipe weight dot (wave-uniform row -> s_load)
  auto dot16 = [&](int row) -> float {
    const float* wr = in_w + (size_t)row*DIN;
    float4 w0 = *(const float4*)(wr),    w1 = *(const float4*)(wr+4);
    float4 w2 = *(const float4*)(wr+8),  w3 = *(const float4*)(wr+12);
    return xr2[0]*w0.x  + xr2[1]*w0.y  + xr2[2]*w0.z  + xr2[3]*w0.w
         + xr2[4]*w1.x  + xr2[5]*w1.y  + xr2[6]*w1.z  + xr2[7]*w1.w
         + xr2[8]*w2.x  + xr2[9]*w2.y  + xr2[10]*w2.z + xr2[11]*w2.w
         + xr2[12]*w3.x + xr2[13]*w3.y + xr2[14]*w3.z + xr2[15]*w3.w;
  };
  size_t gl = (size_t)seq*LL + l0 + lane;
  int tok = l0 + lane;
  float v0ok = (tok >= 2) ? 1.f : 0.f;
  float v1ok = (tok >= 1) ? 1.f : 0.f;
  {
    float zv[8];
#pragma unroll
    for (int j = 0; j < 8; ++j) {
      int row = w*8 + j;
      zv[j] = in_b[row] + dot16(row);
    }
    *(float4*)&zb[gl*NZ + w*8 + 0] = make_float4(zv[0], zv[1], zv[2], zv[3]);
    *(float4*)&zb[gl*NZ + w*8 + 4] = make_float4(zv[4], zv[5], zv[6], zv[7]);
  }
  float dtv;
  {
    int row = NTOT - 4 + w;
    dtv = softplusf(in_b[row] + dt_bias[w] + dot16(row));
  }
  auto convch = [&](int ch) -> float {
    int row = NZ + ch;
    float pm = dot16(row);
    float m1 = __shfl_up(pm, 1, 64);
    float m2 = __shfl_up(pm, 2, 64);
    float2 h01 = *(const float2*)&hp[ch*2];
    if (lane == 0) m1 = h01.y;
    m2 = (lane == 0) ? h01.x : ((lane == 1) ? h01.y : m2);
    float ib = in_b[row];
    float conv = conv_b[ch] + (m2+ib)*v0ok*conv_w[ch*3+0] + (m1+ib)*v1ok*conv_w[ch*3+1]
               + (pm+ib)*conv_w[ch*3+2];
    return siluf(conv);
  };
  // xs head w: registers only
  float xv[8];
#pragma unroll
  for (int j = 0; j < 8; ++j) xv[j] = convch(w*8 + j);
  // B conv channels -> Bt (disjoint from phase-1 aliases)
#pragma unroll
  for (int j = 0; j < 16; ++j) {
    int n = w*16 + j;
    Bt[swz(n, lane)] = convch(NZ + n);
  }
  // C conv channels: regs across the phase barrier (Ct aliases hp/ha)
  float cv[16];
#pragma unroll
  for (int j = 0; j < 16; ++j) cv[j] = convch(NZ + NDS + w*16 + j);
#pragma unroll
  for (int g = 0; g < 4; ++g)
    *(float4*)&Cb[gl*NDS + w*16 + 4*g] = make_float4(cv[4*g], cv[4*g+1], cv[4*g+2], cv[4*g+3]);
  // A-cumsum (register/shuffle only)
  float Aval = -__expf(A_log[w]);
  float Dh = Dp[w];
  float v = dtv * Aval;
#pragma unroll
  for (int off = 1; off < 64; off <<= 1) {
    float t = __shfl_up(v, off, 64);
    if (lane >= off) v += t;
  }
  float acs_l = v;
  float m = __shfl(v, 31, 64);
  float acsLast = __shfl(v, 63, 64);
  float el = __expf(fminf(acs_l - m, 60.f));
  float fl = __expf(fminf(m - acs_l, 60.f));
  __syncthreads();   // === phase barrier: hp/ha reads done ===
#pragma unroll
  for (int j = 0; j < 16; ++j) Ct[swz(w*16 + j, lane)] = cv[j];
  {
    float s1 = dtv*fl;
    float* xe = &xde[(w*64 + lane)*8];
    *(float4*)xe     = make_float4(xv[0]*s1, xv[1]*s1, xv[2]*s1, xv[3]*s1);
    *(float4*)(xe+4) = make_float4(xv[4]*s1, xv[5]*s1, xv[6]*s1, xv[7]*s1);
  }
  __syncthreads();
  int lt = (tid >> 4) << 2, st = (tid & 15) << 2;
  float acc[4][4] = {};
#pragma unroll 4
  for (int n = 0; n < 64; ++n) {
    float4 cvv = *(const float4*)&Ct[swz(n, lt)];
    float4 bvv = *(const float4*)&Bt[swz(n, st)];
    float cc[4] = {cvv.x, cvv.y, cvv.z, cvv.w};
    float bb[4] = {bvv.x, bvv.y, bvv.z, bvv.w};
#pragma unroll
    for (int i2 = 0; i2 < 4; ++i2)
#pragma unroll
      for (int j2 = 0; j2 < 4; ++j2)
        acc[i2][j2] += cc[i2]*bb[j2];
  }
  __syncthreads();
#pragma unroll
  for (int j = 0; j < 4; ++j) {
    *(float4*)&Ct[swz(st + j, lt)] = make_float4(acc[0][j], acc[1][j], acc[2][j], acc[3][j]);
  }
  __syncthreads();
  // ---- merged Yd + states: xde rows via broadcast b128; B via float4/4-tokens ----
  int lg = lane >> 2, lm = lane & 3;
  float ya[8] = {0,0,0,0,0,0,0,0};
  float sa[8] = {0,0,0,0,0,0,0,0};
#pragma unroll 2
  for (int s4 = 0; s4 < 64; s4 += 4) {
    float4 b4 = *(const float4*)&Bt[swz(lane, s4)];   // tokens s4..s4+3, channel=lane
    float bb[4] = {b4.x, b4.y, b4.z, b4.w};
#pragma unroll
    for (int u = 0; u < 4; ++u) {
      int s = s4 + u;
      float g = Ct[(s << 6) + (((lg ^ ((s >> 2) & 15))) << 2 | lm)];
      g = (s <= lane) ? g : 0.f;
      float b = bb[u];
      const float* xr = &xde[(w*64 + s)*8];
      float4 a0 = *(const float4*)xr, a1 = *(const float4*)(xr + 4);
      ya[0] += g*a0.x; ya[1] += g*a0.y; ya[2] += g*a0.z; ya[3] += g*a0.w;
      ya[4] += g*a1.x; ya[5] += g*a1.y; ya[6] += g*a1.z; ya[7] += g*a1.w;
      sa[0] += b*a0.x; sa[1] += b*a0.y; sa[2] += b*a0.z; sa[3] += b*a0.w;
      sa[4] += b*a1.x; sa[5] += b*a1.y; sa[6] += b*a1.z; sa[7] += b*a1.w;
    }
  }
  float* yp = &ybuf[gl*DI + w*8];
  *(float4*)yp     = make_float4(ya[0]*el + Dh*xv[0], ya[1]*el + Dh*xv[1],
                                 ya[2]*el + Dh*xv[2], ya[3]*el + Dh*xv[3]);
  *(float4*)(yp+4) = make_float4(ya[4]*el + Dh*xv[4], ya[5]*el + Dh*xv[5],
                                 ya[6]*el + Dh*xv[6], ya[7]*el + Dh*xv[7]);
  {
    float r2 = __expf(acsLast - m);
    float* sp2 = &states[(((size_t)seq*4 + w)*NCHK + cid)*(size_t)(8*NDS) + lane*8];
    *(float4*)sp2     = make_float4(sa[0]*r2, sa[1]*r2, sa[2]*r2, sa[3]*r2);
    *(float4*)(sp2+4) = make_float4(sa[4]*r2, sa[5]*r2, sa[6]*r2, sa[7]*r2);
  }
  if (lane == 63) cdec[((size_t)seq*4 + w)*NCHK + cid] = __expf(acsLast);
  acsOut[((size_t)seq*4 + w)*LL + l0 + lane] = acs_l;
}

// ---------------- SSD intra-chunk v4 (seed path) ----------------
template<int DS, int NH>
__global__ __launch_bounds__(256) void k_ssd1(
    const float* __restrict__ xs, const float* __restrict__ dtb,
    const float* __restrict__ Bb, const float* __restrict__ Cb,
    const float* __restrict__ A_log, const float* __restrict__ Dp,
    float* __restrict__ ybuf, float* __restrict__ states,
    float* __restrict__ cdec, float* __restrict__ acsOut)
{
  constexpr int DI = NH*8;
  constexpr int NG = DS/4;
  __shared__ __align__(16) float BtBl[DS*64];
  __shared__ __align__(16) float CtGt[64*64];
  __shared__ __align__(16) float xde[NH*64*8];
  int tid = threadIdx.x;
  int cid = blockIdx.x & 63;
  int seq = blockIdx.x >> 6;
  int l0  = cid << 6;
  for (int i = tid; i < 16*DS; i += 256) {
    int ng = i % NG, l = i / NG;
    size_t g = ((size_t)seq*LL + l0 + l)*DS + 4*ng;
    float4 bv = *(const float4*)&Bb[g];
    float4 cv = *(const float4*)&Cb[g];
    BtBl[swz(4*ng+0, l)] = bv.x; BtBl[swz(4*ng+1, l)] = bv.y;
    BtBl[swz(4*ng+2, l)] = bv.z; BtBl[swz(4*ng+3, l)] = bv.w;
    CtGt[swz(4*ng+0, l)] = cv.x; CtGt[swz(4*ng+1, l)] = cv.y;
    CtGt[swz(4*ng+2, l)] = cv.z; CtGt[swz(4*ng+3, l)] = cv.w;
  }
  __syncthreads();
  int lt = (tid >> 4) << 2, st = (tid & 15) << 2;
  float acc[4][4] = {};
#pragma unroll 4
  for (int n = 0; n < DS; ++n) {
    float4 cv = *(const float4*)&CtGt[swz(n, lt)];
    float4 bv = *(const float4*)&BtBl[swz(n, st)];
    float cc[4] = {cv.x, cv.y, cv.z, cv.w};
    float bb[4] = {bv.x, bv.y, bv.z, bv.w};
#pragma unroll
    for (int i2 = 0; i2 < 4; ++i2)
#pragma unroll
      for (int j2 = 0; j2 < 4; ++j2)
        acc[i2][j2] += cc[i2]*bb[j2];
  }
  __syncthreads();
#pragma unroll
  for (int j = 0; j < 4; ++j) {
    float4 gv = make_float4(acc[0][j], acc[1][j], acc[2][j], acc[3][j]);
    *(float4*)&CtGt[swz(st + j, lt)] = gv;
  }
  for (int i = tid; i < 16*DS; i += 256) {
    int ng = i % NG, l = i / NG;
    float4 bv = *(const float4*)&Bb[((size_t)seq*LL + l0 + l)*DS + 4*ng];
    *(float4*)&BtBl[l*DS + 4*ng] = bv;
  }
  __syncthreads();
  int w = tid >> 6, lane = tid & 63;
  if (w < NH) {
    int h = w;
    float dt_l = dtb[((size_t)seq*LL + l0 + lane)*NH + h];
    float Aval = -__expf(A_log[h]);
    float Dh = Dp[h];
    float v = dt_l * Aval;
#pragma unroll
    for (int off = 1; off < 64; off <<= 1) {
      float t = __shfl_up(v, off, 64);
      if (lane >= off) v += t;
    }
    float acs_l = v;
    float m = __shfl(v, 31, 64);
    float acsLast = __shfl(v, 63, 64);
    float el = __expf(fminf(acs_l - m, 60.f));
    float fl = __expf(fminf(m - acs_l, 60.f));
    const float* xp = &xs[((size_t)seq*LL + l0 + lane)*DI + h*8];
    float4 x0 = *(const float4*)xp, x1 = *(const float4*)(xp + 4);
    float s1 = dt_l*fl;
    float* xe = &xde[(h*64 + lane)*8];
    *(float4*)xe     = make_float4(x0.x*s1, x0.y*s1, x0.z*s1, x0.w*s1);
    *(float4*)(xe+4) = make_float4(x1.x*s1, x1.y*s1, x1.z*s1, x1.w*s1);
    int lg = lane >> 2, lm = lane & 3;
    float ya[8] = {0,0,0,0,0,0,0,0};
#pragma unroll 4
    for (int s = 0; s < 64; ++s) {
      float g = CtGt[(s << 6) + ((((lg ^ ((s >> 2) & 15))) << 2) | lm)];
      g = (s <= lane) ? g : 0.f;
      const float* xr = &xde[(h*64 + s)*8];
      float4 a0 = *(const float4*)xr, a1 = *(const float4*)(xr + 4);
      ya[0] += g*a0.x; ya[1] += g*a0.y; ya[2] += g*a0.z; ya[3] += g*a0.w;
      ya[4] += g*a1.x; ya[5] += g*a1.y; ya[6] += g*a1.z; ya[7] += g*a1.w;
    }
    float* yp = &ybuf[((size_t)seq*LL + l0 + lane)*DI + h*8];
    *(float4*)yp     = make_float4(ya[0]*el + Dh*x0.x, ya[1]*el + Dh*x0.y,
                                   ya[2]*el + Dh*x0.z, ya[3]*el + Dh*x0.w);
    *(float4*)(yp+4) = make_float4(ya[4]*el + Dh*x1.x, ya[5]*el + Dh*x1.y,
                                   ya[6]*el + Dh*x1.z, ya[7]*el + Dh*x1.w);
    if (lane < DS) {
      float r2 = __expf(acsLast - m);
      float sa[8] = {0,0,0,0,0,0,0,0};
#pragma unroll 4
      for (int ll = 0; ll < 64; ++ll) {
        float b = BtBl[ll*DS + lane];
        const float* xr = &xde[(h*64 + ll)*8];
        float4 a0 = *(const float4*)xr, a1 = *(const float4*)(xr + 4);
        sa[0] += b*a0.x; sa[1] += b*a0.y; sa[2] += b*a0.z; sa[3] += b*a0.w;
        sa[4] += b*a1.x; sa[5] += b*a1.y; sa[6] += b*a1.z; sa[7] += b*a1.w;
      }
      float* sp2 = &states[(((size_t)seq*NH + h)*NCHK + cid)*(size_t)(8*DS) + lane*8];
      *(float4*)sp2     = make_float4(sa[0]*r2, sa[1]*r2, sa[2]*r2, sa[3]*r2);
      *(float4*)(sp2+4) = make_float4(sa[4]*r2, sa[5]*r2, sa[6]*r2, sa[7]*r2);
    }
    if (lane == 63) cdec[((size_t)seq*NH + h)*NCHK + cid] = __expf(acsLast);
    acsOut[((size_t)seq*NH + h)*LL + l0 + lane] = acs_l;
  }
}

// ---------------- inter-chunk scan (register-pipelined) ----------------
__global__ __launch_bounds__(512) void k_scan(float* __restrict__ st, const float* __restrict__ cd,
                                              int PN)
{
  scan_body(st, cd, PN, blockIdx.x, threadIdx.x);
}

// ---------------- fused LN1 (blocks 0..255) + seed scan (blocks 256..263) ----------------
__global__ __launch_bounds__(256) void k_ln1scan(const float* __restrict__ x,
    const float* __restrict__ w, const float* __restrict__ bb, float* __restrict__ xn,
    float* __restrict__ st, const float* __restrict__ cd)
{
  int tid = threadIdx.x;
  if (blockIdx.x >= B_*64) {
    if (tid < 128) scan_body(st, cd, 128, blockIdx.x - B_*64, tid);
    return;
  }
  __shared__ float tile[128*65];
  __shared__ float mu[64], rs[64];
  int b = blockIdx.x >> 6;
  int l0 = (blockIdx.x & 63) << 6;
  for (int i = tid; i < 8192; i += 256) {
    int l = i & 63, c = i >> 6;
    tile[c*65 + l] = x[((size_t)b*CCH + c)*LL + l0 + l];
  }
  __syncthreads();
  if (tid < 64) {
    float s = 0.f;
    for (int c = 0; c < CCH; ++c) s += tile[c*65 + tid];
    float m = s * (1.f/CCH);
    float v = 0.f;
    for (int c = 0; c < CCH; ++c) { float d = tile[c*65 + tid] - m; v += d*d; }
    mu[tid] = m; rs[tid] = rsqrtf(v*(1.f/CCH) + 1e-5f);
  }
  __syncthreads();
  for (int i = tid; i < 8192; i += 256) {
    int c = i & 127, l = i >> 7;
    xn[((size_t)b*LL + l0 + l)*CCH + c] = (tile[c*65 + l] - mu[l])*rs[l]*w[c] + bb[c];
  }
}

// ======= FUSED Yo + gating + RMSNorm + out-proj v5 (R7 best) =======
template<int DS, int NH, int DOUT>
__global__ __launch_bounds__(256, 4) void k_yogate(
    const float* __restrict__ ybuf, const float* __restrict__ Cb,
    const float* __restrict__ prevSt, const float* __restrict__ acsG,
    const float* __restrict__ zb,
    const float* __restrict__ rms_w, const float* __restrict__ out_w,
    float* __restrict__ dst, int resMode, const float* __restrict__ res,
    const float* __restrict__ skipPtr, float* __restrict__ gmP)
{
  constexpr int DI = NH*8;
  constexpr int NG = DS/4;
  constexpr int DIP = DI + 4;
  constexpr int OQ = DOUT/4;
  __shared__ __align__(16) float Ct2[DS*64];
  __shared__ __align__(16) float pvs[NH*DS*8];
  __shared__ __align__(16) float gt[64*DIP];
  __shared__ float ps[NH*64];
  __shared__ __align__(16) float ow[DOUT*DI];
  __shared__ float rwl[DI];
  int tid = threadIdx.x;
  int cid = blockIdx.x & 63;
  int seq = blockIdx.x >> 6;
  int l0  = cid << 6;
  int lane = tid & 63, w = tid >> 6;
  // ---- LDS staging ----
  for (int i = tid; i < 16*DS; i += 256) {
    int ng = i % NG, l = i / NG;
    float4 cv = *(const float4*)&Cb[((size_t)seq*LL + l0 + l)*DS + 4*ng];
    Ct2[swz(4*ng+0, l)] = cv.x; Ct2[swz(4*ng+1, l)] = cv.y;
    Ct2[swz(4*ng+2, l)] = cv.z; Ct2[swz(4*ng+3, l)] = cv.w;
  }
  for (int i = tid; i < NH*DS*2; i += 256) {
    int h = i / (DS*2), o4 = i % (DS*2);
    float4 pv = *(const float4*)&prevSt[(((size_t)seq*NH + h)*NCHK + cid)*(size_t)(DS*8) + o4*4];
    *(float4*)&pvs[h*DS*8 + o4*4] = pv;
  }
  for (int i = tid; i < DOUT*DI/4; i += 256)
    *(float4*)&ow[i*4] = *(const float4*)&out_w[i*4];
  for (int i = tid; i < DI; i += 256) rwl[i] = rms_w[i];
  __syncthreads();
  // ---- phase 1: Yo + gating, 4-token x 2-j tile per lane ----
  if (w < NH) {
    int tg = (lane & 15) << 2;     // 4 tokens tg..tg+3
    int jp = (lane >> 4) << 1;     // j-pair jp, jp+1
    float a00=0,a01=0,a10=0,a11=0,a20=0,a21=0,a30=0,a31=0;
#pragma unroll 4
    for (int n = 0; n < DS; ++n) {
      float4 c4 = *(const float4*)&Ct2[swz(n, tg)];
      float2 p2 = *(const float2*)&pvs[(w*DS + n)*8 + jp];
      a00 += c4.x*p2.x; a01 += c4.x*p2.y;
      a10 += c4.y*p2.x; a11 += c4.y*p2.y;
      a20 += c4.z*p2.x; a21 += c4.z*p2.y;
      a30 += c4.w*p2.x; a31 += c4.w*p2.y;
    }
    float ac[4][2] = {{a00,a01},{a10,a11},{a20,a21},{a30,a31}};
    float psum[4];
#pragma unroll
    for (int t = 0; t < 4; ++t) {
      int token = tg + t;
      float el = __expf(acsG[((size_t)seq*NH + w)*LL + l0 + token]);
      size_t gi = ((size_t)seq*LL + l0 + token)*DI + w*8 + jp;
      float2 y2 = *(const float2*)&ybuf[gi];
      float2 z2 = *(const float2*)&zb[gi];
      float g0 = (y2.x + el*ac[t][0]) * siluf(z2.x);
      float g1 = (y2.y + el*ac[t][1]) * siluf(z2.y);
      *(float2*)&gt[token*DIP + w*8 + jp] = make_float2(g0, g1);
      psum[t] = g0*g0 + g1*g1;
    }
#pragma unroll
    for (int t = 0; t < 4; ++t) {
      psum[t] += __shfl_xor(psum[t], 16, 64);
      psum[t] += __shfl_xor(psum[t], 32, 64);
    }
    if (lane < 16) {
#pragma unroll
      for (int t = 0; t < 4; ++t) ps[w*64 + tg + t] = psum[t];
    }
  }
  __syncthreads();
  // ---- phase 2: RMSNorm + out-proj (token = lane, channel group = wave) ----
  int tok = lane, q = w;
  float rsum = 0.f;
#pragma unroll
  for (int h = 0; h < NH; ++h) rsum += ps[h*64 + tok];
  float r = rsqrtf(rsum*(1.f/DI) + 1e-5f);
  float gr[DI];
#pragma unroll
  for (int k = 0; k < DI/4; ++k) {
    float4 v = *(const float4*)&gt[tok*DIP + 4*k];
    gr[4*k+0] = v.x*r*rwl[4*k+0];
    gr[4*k+1] = v.y*r*rwl[4*k+1];
    gr[4*k+2] = v.z*r*rwl[4*k+2];
    gr[4*k+3] = v.w*r*rwl[4*k+3];
  }
  int l = l0 + tok;
  const float* rp = nullptr; float skip = 1.f;
  if (resMode == 1) rp = res + ((size_t)seq*LL + l)*DOUT + q*OQ;
  else if (resMode == 2) {
    int s = seq / B_, b = seq % B_;
    rp = res + ((size_t)b*LL + l)*CCH + s*DOUT + q*OQ;
    skip = skipPtr[0];
  }
  float ov[OQ];
#pragma unroll
  for (int j = 0; j < OQ; ++j) {
    int o = q*OQ + j;
    const float* wr = &ow[o*DI];
    float acc2 = 0.f;
#pragma unroll
    for (int k = 0; k < DI/4; ++k) {
      float4 wv = *(const float4*)(wr + 4*k);
      acc2 += gr[4*k]*wv.x + gr[4*k+1]*wv.y + gr[4*k+2]*wv.z + gr[4*k+3]*wv.w;
    }
    if (rp) acc2 += skip * rp[j];
    ov[j] = acc2;
  }
  float* dp = &dst[((size_t)seq*LL + l)*DOUT + q*OQ];
  if constexpr (OQ == 4) *(float4*)dp = make_float4(ov[0], ov[1], ov[2], ov[3]);
  else *(float2*)dp = make_float2(ov[0], ov[1]);
  // gm partial sums: per-wave token reduce, contention-free per-block scatter
  if (gmP) {
#pragma unroll
    for (int j = 0; j < OQ; ++j) {
      float sv = ov[j];
#pragma unroll
      for (int off = 32; off > 0; off >>= 1) sv += __shfl_down(sv, off, 64);
      if (tok == 0) gmP[(((size_t)seq*NCHK + cid))*DOUT + q*OQ + j] = sv;
    }
  }
}

// ---------------- gmix: reduce gmP over chunks, softmax-mix, scale 1/LL ----------------
__global__ __launch_bounds__(256) void k_mix(const float* __restrict__ gmP,
    const float* __restrict__ crossW, float* __restrict__ gmix)
{
  __shared__ float wsm[64];
  __shared__ float gs[512];
  int tid = threadIdx.x;
  // phase A: reduce over the 64 chunks
  for (int i = tid; i < 512; i += 256) {
    int sq = i >> 4, c = i & 15;
    const float* p = gmP + ((size_t)sq*NCHK)*16 + c;
    float acc = 0.f;
    for (int cid = 0; cid < NCHK; ++cid) acc += p[cid*16];
    gs[i] = acc;
  }
  if (tid < 8) {
    float mx = -1e30f;
    for (int p = 0; p < 8; ++p) mx = fmaxf(mx, crossW[tid*8 + p]);
    float e[8]; float s = 0.f;
    for (int p = 0; p < 8; ++p) { e[p] = __expf(crossW[tid*8 + p] - mx); s += e[p]; }
    for (int p = 0; p < 8; ++p) wsm[tid*8 + p] = e[p] / s;
  }
  __syncthreads();
  for (int i = tid; i < 512; i += 256) {
    int c = i & 15; int bb = (i >> 4) & 3; int p = i >> 6;
    float acc = 0.f;
    for (int q = 0; q < 8; ++q)
      acc += gs[(q*B_ + bb)*16 + c] * (1.f/LL) * wsm[q*8 + p];
    gmix[((size_t)(p*B_ + bb))*16 + c] = acc;
  }
}

// ---------------- assemble ys+gmix, LN2, + (x + detok(gf2)) -> outb[b,c,l] ----------------
__global__ __launch_bounds__(256) void k_out2(const float* __restrict__ ys,
    const float* __restrict__ gmix, const float* __restrict__ w, const float* __restrict__ bb,
    const float* __restrict__ x, const float* __restrict__ gf2,
    const float* __restrict__ dw, const float* __restrict__ db,
    float* __restrict__ outb)
{
  __shared__ float tile[128*65];
  __shared__ float mu[64], rs[64];
  int tid = threadIdx.x;
  int b = blockIdx.x >> 6;
  int l0 = (blockIdx.x & 63) << 6;
  for (int i = tid; i < 8192; i += 256) {
    int c = i & 15; int l = (i >> 4) & 63; int s = i >> 10;
    int seq = s*B_ + b;
    tile[(s*16 + c)*65 + l] = ys[((size_t)seq*LL + l0 + l)*16 + c] + gmix[(size_t)seq*16 + c];
  }
  __syncthreads();
  if (tid < 64) {
    float sm = 0.f;
    for (int c = 0; c < 128; ++c) sm += tile[c*65 + tid];
    float m = sm * (1.f/128.f);
    float v = 0.f;
    for (int c = 0; c < 128; ++c) { float d = tile[c*65 + tid] - m; v += d*d; }
    mu[tid] = m; rs[tid] = rsqrtf(v*(1.f/128.f) + 1e-5f);
  }
  __syncthreads();
  int lfix = tid & 63;
  float g8[8];
  {
    const float* gp = gf2 + ((size_t)b*LL + l0 + lfix)*8;
#pragma unroll
    for (int k = 0; k < 8; ++k) g8[k] = gp[k];
  }
  for (int i = tid; i < 8192; i += 256) {
    int l = i & 63, c = i >> 6;
    size_t gi = ((size_t)b*CCH + c)*LL + l0 + l;
    float det = db[c];
#pragma unroll
    for (int k = 0; k < 8; ++k) det += g8[k]*dw[c*8 + k];
    outb[gi] = (tile[c*65 + l] - mu[l])*rs[l]*w[c] + bb[c] + x[gi] + det;
  }
}

// ---------------- fc1: register-tiled GEMM, transposed weight tile ----------------
__global__ __launch_bounds__(256) void k_fc1(const float* __restrict__ src,
    const float* __restrict__ w, const float* __restrict__ bias, float* __restrict__ dst)
{
  constexpr int WTP = 68;
  __shared__ float st[128*64];
  __shared__ __align__(16) float wtT[128*WTP];
  int tid = threadIdx.x;
  int blk = blockIdx.x;
  int ot = blk & 3;
  int lt = (blk >> 2) & 63;
  int b  = blk >> 8;
  int l0 = lt << 6, o0 = ot << 6;
  for (int i = tid; i < 8192; i += 256) {
    int l = i & 63, c = i >> 6;
    st[c*64 + l] = src[((size_t)b*CCH + c)*LL + l0 + l];
  }
  for (int i = tid; i < 8192; i += 256) {
    int c = i & 127, o = i >> 7;
    wtT[c*WTP + o] = w[(size_t)(o0 + o)*128 + c];
  }
  __syncthreads();
  int l4 = (tid & 15) << 2, o4 = (tid >> 4) << 2;
  float a0[4] = {}, a1[4] = {}, a2[4] = {}, a3[4] = {};
#pragma unroll 4
  for (int c = 0; c < 128; ++c) {
    float4 sv = *(float4*)&st[c*64 + l4];
    float4 wv = *(float4*)&wtT[c*WTP + o4];
    a0[0] += wv.x*sv.x; a0[1] += wv.x*sv.y; a0[2] += wv.x*sv.z; a0[3] += wv.x*sv.w;
    a1[0] += wv.y*sv.x; a1[1] += wv.y*sv.y; a1[2] += wv.y*sv.z; a1[3] += wv.y*sv.w;
    a2[0] += wv.z*sv.x; a2[1] += wv.z*sv.y; a2[2] += wv.z*sv.z; a2[3] += wv.z*sv.w;
    a3[0] += wv.w*sv.x; a3[1] += wv.w*sv.y; a3[2] += wv.w*sv.z; a3[3] += wv.w*sv.w;
  }
  float* rows[4] = {a0, a1, a2, a3};
#pragma unroll
  for (int j = 0; j < 4; ++j) {
    int o = o0 + o4 + j;
    float bi = bias[o];
    float* a = rows[j];
    *(float4*)&dst[((size_t)b*256 + o)*LL + l0 + l4] =
        make_float4(a[0]+bi, a[1]+bi, a[2]+bi, a[3]+bi);
  }
}

// ---------------- depthwise 3x3 + gelu, LDS-tiled ----------------
__global__ __launch_bounds__(256) void k_dw(const float* __restrict__ h1,
    const float* __restrict__ w, const float* __restrict__ bias, float* __restrict__ h2)
{
  __shared__ float tile[66*66];
  int tid = threadIdx.x;
  int blk = blockIdx.x;
  const float* base = h1 + (size_t)blk*LL;
  const float* wp = w + (blk & 255)*9;
  float bi = bias[blk & 255];
  for (int i = tid; i < 66*66; i += 256) {
    int r = i / 66, cc = i % 66;
    int gr = r - 1, gc = cc - 1;
    tile[i] = (gr >= 0 && gr < HH && gc >= 0 && gc < WW) ? base[gr*WW + gc] : 0.f;
  }
  float w00 = wp[0], w01 = wp[1], w02 = wp[2];
  float w10 = wp[3], w11 = wp[4], w12 = wp[5];
  float w20 = wp[6], w21 = wp[7], w22 = wp[8];
  __syncthreads();
  float* outp = h2 + (size_t)blk*LL;
#pragma unroll
  for (int k = 0; k < 16; ++k) {
    int j = tid + k*256;
    int row = j >> 6, col = j & 63;
    const float* t0 = &tile[row*66 + col];
    float acc = t0[0]*w00  + t0[1]*w01  + t0[2]*w02
              + t0[66]*w10 + t0[67]*w11 + t0[68]*w12
              + t0[132]*w20 + t0[133]*w21 + t0[134]*w22;
    float v = acc + bi;
    float u = 0.7978845608028654f*(v + 0.044715f*v*v*v);
    float e = __expf(2.f*u);
    float th = 1.f - 2.f/(e + 1.f);
    outp[j] = 0.5f*v*(1.f + th);
  }
}

// ---------------- fc2: register-tiled GEMM, transposed weight tile ----------------
__global__ __launch_bounds__(256) void k_fc2(const float* __restrict__ h2,
    const float* __restrict__ w, const float* __restrict__ bias,
    const float* __restrict__ resid, float* __restrict__ dst)
{
  constexpr int WTP = 36;
  __shared__ float st[128*64];
  __shared__ __align__(16) float wtT[256*WTP];
  int tid = threadIdx.x;
  int blk = blockIdx.x;
  int ct = blk & 3;
  int lt = (blk >> 2) & 63;
  int b  = blk >> 8;
  int l0 = lt << 6, c0 = ct << 5;
  for (int i = tid; i < 32*256; i += 256) {
    int o = i & 255, c = i >> 8;
    wtT[o*WTP + c] = w[(size_t)(c0 + c)*256 + o];
  }
  int l4 = (tid & 15) << 2, c2 = (tid >> 4) << 1;
  float a0[4] = {}, a1[4] = {};
  for (int ko = 0; ko < 256; ko += 128) {
    __syncthreads();
    for (int i = tid; i < 8192; i += 256) {
      int l = i & 63, o = i >> 6;
      st[o*64 + l] = h2[((size_t)b*256 + ko + o)*LL + l0 + l];
    }
    __syncthreads();
#pragma unroll 4
    for (int o = 0; o < 128; ++o) {
      float4 sv = *(float4*)&st[o*64 + l4];
      float2 wv = *(float2*)&wtT[(ko + o)*WTP + c2];
      a0[0] += wv.x*sv.x; a0[1] += wv.x*sv.y; a0[2] += wv.x*sv.z; a0[3] += wv.x*sv.w;
      a1[0] += wv.y*sv.x; a1[1] += wv.y*sv.y; a1[2] += wv.y*sv.z; a1[3] += wv.y*sv.w;
    }
  }
  float* rows[2] = {a0, a1};
#pragma unroll
  for (int j = 0; j < 2; ++j) {
    int c = c0 + c2 + j;
    float bi = bias[c];
    size_t gi = ((size_t)b*CCH + c)*LL + l0 + l4;
    float4 rv = *(const float4*)&resid[gi];
    float* a = rows[j];
    *(float4*)&dst[gi] = make_float4(a[0]+bi+rv.x, a[1]+bi+rv.y, a[2]+bi+rv.z, a[3]+bi+rv.w);
  }
}

extern "C" void kernel_launch(void* const* d_in, const int* in_sizes, int n_in,
                              void* d_out, int out_size, void* d_ws, size_t ws_size,
                              hipStream_t stream) {
  (void)in_sizes; (void)n_in; (void)out_size; (void)ws_size;
  const float* x        = (const float*)d_in[0];
  const float* tok_w    = (const float*)d_in[1];
  const float* tok_b    = (const float*)d_in[2];
  const float* detok_w  = (const float*)d_in[3];
  const float* detok_b  = (const float*)d_in[4];
  const float* sm_in_w  = (const float*)d_in[5];
  const float* sm_in_b  = (const float*)d_in[6];
  const float* sm_conv_w= (const float*)d_in[7];
  const float* sm_conv_b= (const float*)d_in[8];
  const float* sm_A_log = (const float*)d_in[9];
  const float* sm_D     = (const float*)d_in[10];
  const float* sm_dt_b  = (const float*)d_in[11];
  const float* sm_rms_w = (const float*)d_in[12];
  const float* sm_out_w = (const float*)d_in[13];
  const float* cm_in_w  = (const float*)d_in[14];
  const float* cm_in_b  = (const float*)d_in[15];
  const float* cm_conv_w= (const float*)d_in[16];
  const float* cm_conv_b= (const float*)d_in[17];
  const float* cm_A_log = (const float*)d_in[18];
  const float* cm_D     = (const float*)d_in[19];
  const float* cm_dt_b  = (const float*)d_in[20];
  const float* cm_rms_w = (const float*)d_in[21];
  const float* cm_out_w = (const float*)d_in[22];
  const float* cross_W  = (const float*)d_in[23];
  const float* n1w      = (const float*)d_in[24];
  const float* n1b      = (const float*)d_in[25];
  const float* n2w      = (const float*)d_in[26];
  const float* n2b      = (const float*)d_in[27];
  const float* fc1w     = (const float*)d_in[28];
  const float* fc1b     = (const float*)d_in[29];
  const float* dww      = (const float*)d_in[30];
  const float* dwb      = (const float*)d_in[31];
  const float* fc2w     = (const float*)d_in[32];
  const float* fc2b     = (const float*)d_in[33];
  const float* skp      = (const float*)d_in[34];
  float* ws  = (float*)d_ws;
  float* out = (float*)d_out;

  const size_t SGF0 = 0;
  const size_t SOUTn= 131072;
  const size_t XN   = 2097152;
  const size_t YS   = 4194304;
  const size_t OUTB = 6291456;
  const size_t GMIX = 8389120;
  const size_t GMP  = 8389632;           // 32*64*16 = 32768 floats
  const size_t SCR  = GMP + 32768;
  const size_t CZ   = SCR;
  const size_t CCF  = CZ   + 4194304;
  const size_t CACS = CCF  + 8388608;
  const size_t CST  = CACS + 2097152;
  const size_t CCD  = CST  + 4194304;
  const size_t CY   = CCD  + 8192;
  const size_t XB   = CY   + 4194304;
  const size_t SZ   = SCR;
  const size_t SDT  = SZ  + 262144;
  const size_t SXS  = SDT + 32768;
  const size_t SB   = SXS + 262144;
  const size_t SC   = SB  + 262144;
  const size_t SACS = SC  + 262144;
  const size_t SST  = SACS + 32768;
  const size_t SCD  = SST + 65536;
  const size_t SY   = SCD + 512;
  const size_t H1 = SCR;
  const size_t H2 = SCR + 4194304;

  // ===== seed path =====
  k_seedtok<<<B_*64, 256, 0, stream>>>(x, tok_w, tok_b, ws + SGF0);
  k_inproj<8,16,16,2><<<B_*64, 256, 0, stream>>>(ws + SGF0, 0, sm_in_w, sm_in_b, sm_conv_w,
      sm_conv_b, sm_dt_b, ws + SZ, ws + SDT, ws + SXS, ws + SB, ws + SC);
  k_ssd1<16,2><<<B_*NCHK, 256, 0, stream>>>(ws + SXS, ws + SDT, ws + SB, ws + SC,
      sm_A_log, sm_D, ws + SY, ws + SST, ws + SCD, ws + SACS);
  // fused: LN1 (256 blocks) + seed inter-chunk scan (8 blocks) — independent work,
  // hides the underfilled scan under LN1's memory phase
  k_ln1scan<<<B_*64 + B_*2, 256, 0, stream>>>(x, n1w, n1b, ws + XN, ws + SST, ws + SCD);
  k_yogate<16,2,8><<<B_*NCHK, 256, 0, stream>>>(ws + SY, ws + SC, ws + SST, ws + SACS,
      ws + SZ, sm_rms_w, sm_out_w, ws + SOUTn, 1, ws + SGF0, skp, nullptr);

  // ===== cascade layer 0 =====
  k_inssd<<<32*NCHK, 256, 0, stream>>>(ws + XN, 1, cm_in_w, cm_in_b, cm_conv_w,
      cm_conv_b, cm_dt_b, cm_A_log, cm_D, ws + CZ, ws + CCF,
      ws + CY, ws + CST, ws + CCD, ws + CACS);
  k_scan<<<32*4, 512, 0, stream>>>(ws + CST, ws + CCD, 512);
  k_yogate<64,4,16><<<32*NCHK, 256, 0, stream>>>(ws + CY, ws + CCF, ws + CST, ws + CACS,
      ws + CZ, cm_rms_w, cm_out_w, ws + XB, 0, nullptr, skp, nullptr);

  // ===== cascade layer 1 =====
  k_inssd<<<32*NCHK, 256, 0, stream>>>(ws + XB, 0, cm_in_w + 3136, cm_in_b + 196,
      cm_conv_w + 480, cm_conv_b + 160, cm_dt_b + 4, cm_A_log + 4, cm_D + 4, ws + CZ, ws + CCF,
      ws + CY, ws + CST, ws + CCD, ws + CACS);
  k_scan<<<32*4, 512, 0, stream>>>(ws + CST, ws + CCD, 512);
  k_yogate<64,4,16><<<32*NCHK, 256, 0, stream>>>(ws + CY, ws + CCF, ws + CST, ws + CACS,
      ws + CZ, cm_rms_w + 32, cm_out_w + 512, ws + YS, 2, ws + XN, skp, ws + GMP);

  // ===== cross mix + norm2 + (fused detok seed) =====
  k_mix<<<1, 256, 0, stream>>>(ws + GMP, cross_W, ws + GMIX);
  k_out2<<<B_*64, 256, 0, stream>>>(ws + YS, ws + GMIX, n2w, n2b,
      x, ws + SOUTn, detok_w, detok_b, ws + OUTB);

  // ===== FFN =====
  k_fc1<<<B_*64*4, 256, 0, stream>>>(ws + OUTB, fc1w, fc1b, ws + H1);
  k_dw<<<B_*256, 256, 0, stream>>>(ws + H1, dww, dwb, ws + H2);
  k_fc2<<<B_*64*4, 256, 0, stream>>>(ws + H2, fc2w, fc2b, ws + OUTB, out);
}